// Round 8
// baseline (1371.259 us; speedup 1.0000x reference)
//
#include <hip/hip_runtime.h>
#include <math.h>

#define CN 128   // captions
#define INN 128  // images
#define LN 48    // words
#define RN 36    // regions
#define DN 1024  // feature dim
#define TI 4     // images per attn block tile
#define RT 144   // TI*RN
#define MT 6144  // CN*LN
#define NT 4608  // INN*RN
#define EPSF 1e-8f
#define LSM 9.0f
#define LLSE 6.0f

__device__ __forceinline__ float leaky(float x){ return x > 0.f ? x : 0.1f*x; }
__device__ __forceinline__ float dot4(float4 a, float4 b){
  return a.x*b.x + a.y*b.y + a.z*b.z + a.w*b.w;
}

typedef const __attribute__((address_space(1))) unsigned int* gp_t;
typedef __attribute__((address_space(3))) unsigned int* lp_t;
__device__ __forceinline__ void gload16u(const ushort* g, ushort* l) {
  __builtin_amdgcn_global_load_lds((gp_t)g, (lp_t)l, 16, 0, 0);
}

typedef short s16x8 __attribute__((ext_vector_type(8)));
typedef float f32x4 __attribute__((ext_vector_type(4)));

// ---------------- Kernel 0: fp32 -> bf16 hi/lo split (RNE) ----------------
__global__ __launch_bounds__(256) void conv_kernel(
    const float* __restrict__ caps, const float* __restrict__ imgs,
    ushort* __restrict__ aHi, ushort* __restrict__ aLo,
    ushort* __restrict__ bHi, ushort* __restrict__ bLo)
{
  const int NA = MT*DN/4, NB = NT*DN/4;
  for (int i = blockIdx.x*256 + threadIdx.x; i < NA + NB; i += gridDim.x*256) {
    const float4 v = (i < NA) ? ((const float4*)caps)[i] : ((const float4*)imgs)[i - NA];
    const float fv[4] = {v.x, v.y, v.z, v.w};
    ushort hh[4], ll[4];
    #pragma unroll
    for (int e = 0; e < 4; ++e) {
      const unsigned u = __float_as_uint(fv[e]);
      const ushort hi = (ushort)((u + 0x7fffu + ((u>>16)&1u)) >> 16);
      const float res = fv[e] - __uint_as_float((unsigned)hi << 16);
      const unsigned u2 = __float_as_uint(res);
      hh[e] = hi;
      ll[e] = (ushort)((u2 + 0x7fffu + ((u2>>16)&1u)) >> 16);
    }
    const ushort4 h = make_ushort4(hh[0],hh[1],hh[2],hh[3]);
    const ushort4 lo = make_ushort4(ll[0],ll[1],ll[2],ll[3]);
    if (i < NA) { ((ushort4*)aHi)[i] = h;    ((ushort4*)aLo)[i] = lo; }
    else        { ((ushort4*)bHi)[i-NA] = h; ((ushort4*)bLo)[i-NA] = lo; }
  }
}

// ---------------- Kernel 1: Gram matrices + norms (fp32, LDS D-tiled) ----------------
__global__ __launch_bounds__(256) void gram_kernel(
    const float* __restrict__ imgs, const float* __restrict__ caps,
    float* __restrict__ gI, float* __restrict__ nI,
    float* __restrict__ gC, float* __restrict__ nC)
{
  __shared__ __align__(16) float L[LN*132];   // max 48 rows x 132
  const int b = blockIdx.x, tid = threadIdx.x;
  if (b < INN) {
    const float* base = imgs + (size_t)b*RN*DN;
    const int rg = tid/12, cg = tid - (tid/12)*12;   // 18x12 teams, 216 active
    const bool active = tid < 216;
    float a[2][3];
    #pragma unroll
    for (int u = 0; u < 2; ++u)
      #pragma unroll
      for (int v = 0; v < 3; ++v) a[u][v] = 0.f;
    for (int d0 = 0; d0 < DN; d0 += 128) {
      __syncthreads();
      for (int idx = tid; idx < RN*32; idx += 256) {
        const int row = idx >> 5, ch = idx & 31;
        *(float4*)&L[row*132 + ch*4] = *(const float4*)(base + row*DN + d0 + ch*4);
      }
      __syncthreads();
      if (active) {
        const float* r0 = &L[(2*rg)*132],   * r1 = &L[(2*rg+1)*132];
        const float* c0 = &L[(3*cg)*132],   * c1 = &L[(3*cg+1)*132], * c2 = &L[(3*cg+2)*132];
        #pragma unroll
        for (int k = 0; k < 32; ++k) {
          const float4 x0 = *(const float4*)(r0 + k*4);
          const float4 x1 = *(const float4*)(r1 + k*4);
          const float4 y0 = *(const float4*)(c0 + k*4);
          const float4 y1 = *(const float4*)(c1 + k*4);
          const float4 y2 = *(const float4*)(c2 + k*4);
          a[0][0] += dot4(x0,y0); a[0][1] += dot4(x0,y1); a[0][2] += dot4(x0,y2);
          a[1][0] += dot4(x1,y0); a[1][1] += dot4(x1,y1); a[1][2] += dot4(x1,y2);
        }
      }
    }
    if (active) {
      float* gb = gI + (size_t)b*RN*RN;
      #pragma unroll
      for (int u = 0; u < 2; ++u)
        #pragma unroll
        for (int v = 0; v < 3; ++v) {
          const int r = 2*rg + u, s = 3*cg + v;
          gb[r*RN + s] = a[u][v];
          if (r == s) nI[b*RN + r] = sqrtf(fmaxf(a[u][v], 1e-16f));
        }
    }
  } else {
    const int c = b - INN;
    const float* base = caps + (size_t)c*LN*DN;
    const int rg = tid >> 4, cg = tid & 15;          // 16x16 teams, all 256 active
    float a[3][3];
    #pragma unroll
    for (int u = 0; u < 3; ++u)
      #pragma unroll
      for (int v = 0; v < 3; ++v) a[u][v] = 0.f;
    for (int d0 = 0; d0 < DN; d0 += 128) {
      __syncthreads();
      for (int idx = tid; idx < LN*32; idx += 256) {
        const int row = idx >> 5, ch = idx & 31;
        *(float4*)&L[row*132 + ch*4] = *(const float4*)(base + row*DN + d0 + ch*4);
      }
      __syncthreads();
      const float* r0 = &L[(3*rg)*132],   * r1 = &L[(3*rg+1)*132], * r2 = &L[(3*rg+2)*132];
      const float* c0 = &L[(3*cg)*132],   * c1 = &L[(3*cg+1)*132], * c2 = &L[(3*cg+2)*132];
      #pragma unroll
      for (int k = 0; k < 32; ++k) {
        const float4 x0 = *(const float4*)(r0 + k*4);
        const float4 x1 = *(const float4*)(r1 + k*4);
        const float4 x2 = *(const float4*)(r2 + k*4);
        const float4 y0 = *(const float4*)(c0 + k*4);
        const float4 y1 = *(const float4*)(c1 + k*4);
        const float4 y2 = *(const float4*)(c2 + k*4);
        a[0][0] += dot4(x0,y0); a[0][1] += dot4(x0,y1); a[0][2] += dot4(x0,y2);
        a[1][0] += dot4(x1,y0); a[1][1] += dot4(x1,y1); a[1][2] += dot4(x1,y2);
        a[2][0] += dot4(x2,y0); a[2][1] += dot4(x2,y1); a[2][2] += dot4(x2,y2);
      }
    }
    float* gb = gC + (size_t)c*LN*LN;
    #pragma unroll
    for (int u = 0; u < 3; ++u)
      #pragma unroll
      for (int v = 0; v < 3; ++v) {
        const int r = 3*rg + u, s = 3*cg + v;
        gb[r*LN + s] = a[u][v];
        if (r == s) nC[c*LN + r] = sqrtf(fmaxf(a[u][v], 1e-16f));
      }
  }
}

// ---------------- Kernel 2: dots GEMM via bf16x3 MFMA ----------------
__global__ __launch_bounds__(256) void dots_gemm_mfma(
    const ushort* __restrict__ aHi, const ushort* __restrict__ aLo,
    const ushort* __restrict__ bHi, const ushort* __restrict__ bLo,
    float* __restrict__ dots, int arow0)
{
  __shared__ __align__(16) ushort sT[16384];   // Ah Al Bh Bl, 8KB each
  const int tid = threadIdx.x;
  const int wv = tid >> 6, lane = tid & 63;
  const int l15 = lane & 15, kg = lane >> 4;
  const int wr = wv >> 1, wc = wv & 1;
  const int M0 = blockIdx.y * 128;
  const int N0 = blockIdx.x * 128;

  int offA[4], offB[4];
  #pragma unroll
  for (int f = 0; f < 4; ++f) {
    const int rA = wr*64 + f*16 + l15;
    offA[f] = rA*32 + ((kg ^ ((rA>>1)&3)) << 3);
    const int rB = wc*64 + f*16 + l15;
    offB[f] = rB*32 + ((kg ^ ((rB>>1)&3)) << 3);
  }
  int srow[2], sgk[2]; unsigned dOff[2];
  #pragma unroll
  for (int h = 0; h < 2; ++h) {
    const int ch = h*256 + wv*64 + lane;
    const int row = ch >> 2, gp = ch & 3;
    srow[h] = row;
    sgk[h] = (gp ^ ((row>>1)&3)) * 8;
    dOff[h] = (unsigned)(h*256 + wv*64) * 8;
  }

  f32x4 acc[4][4];
  #pragma unroll
  for (int mf = 0; mf < 4; ++mf)
    #pragma unroll
    for (int nf = 0; nf < 4; ++nf) acc[mf][nf] = (f32x4){0.f,0.f,0.f,0.f};

  const size_t aR = (size_t)(arow0 + M0);
  for (int k0 = 0; k0 < DN; k0 += 32) {
    __syncthreads();
    #pragma unroll
    for (int h = 0; h < 2; ++h) {
      const size_t ao = (aR + srow[h])*DN + k0 + sgk[h];
      const size_t bo = ((size_t)(N0 + srow[h]))*DN + k0 + sgk[h];
      gload16u(aHi + ao, sT + dOff[h]);
      gload16u(aLo + ao, sT + 4096 + dOff[h]);
      gload16u(bHi + bo, sT + 8192 + dOff[h]);
      gload16u(bLo + bo, sT + 12288 + dOff[h]);
    }
    asm volatile("s_waitcnt vmcnt(0)" ::: "memory");
    __syncthreads();
    s16x8 ah[4], al[4], bh[4], bl[4];
    #pragma unroll
    for (int f = 0; f < 4; ++f) {
      ah[f] = *(const s16x8*)&sT[offA[f]];
      al[f] = *(const s16x8*)&sT[4096 + offA[f]];
      bh[f] = *(const s16x8*)&sT[8192 + offB[f]];
      bl[f] = *(const s16x8*)&sT[12288 + offB[f]];
    }
    #pragma unroll
    for (int mf = 0; mf < 4; ++mf)
      #pragma unroll
      for (int nf = 0; nf < 4; ++nf) {
        acc[mf][nf] = __builtin_amdgcn_mfma_f32_16x16x32_bf16(ah[mf], bh[nf], acc[mf][nf], 0,0,0);
        acc[mf][nf] = __builtin_amdgcn_mfma_f32_16x16x32_bf16(ah[mf], bl[nf], acc[mf][nf], 0,0,0);
        acc[mf][nf] = __builtin_amdgcn_mfma_f32_16x16x32_bf16(al[mf], bh[nf], acc[mf][nf], 0,0,0);
      }
  }
  #pragma unroll
  for (int mf = 0; mf < 4; ++mf)
    #pragma unroll
    for (int nf = 0; nf < 4; ++nf) {
      const int n = N0 + wc*64 + nf*16 + l15;
      #pragma unroll
      for (int r = 0; r < 4; ++r) {
        const int m = M0 + wr*64 + mf*16 + kg*4 + r;
        dots[(size_t)m*NT + n] = acc[mf][nf][r];
      }
    }
}

// ---------------- Kernel 3: attention + scores ----------------
// Wave iw owns image iw (G wave-uniform); each 4-lane team batches 3 rows so
// every G-row ds_read_b128 triple is amortized over 3 rows (qq LDS traffic /3).
__global__ __launch_bounds__(256) void attn_kernel(
    const float* __restrict__ dots, const int* __restrict__ cap_lens,
    const float* __restrict__ gI, const float* __restrict__ nI,
    const float* __restrict__ gC, const float* __restrict__ nC,
    float* __restrict__ scores, int cbase)
{
  __shared__ float sDots[LN][RT+1];
  __shared__ __align__(16) float sGi4[TI*RN*48];
  __shared__ __align__(16) float sGc[LN*48];
  __shared__ float sColInv[TI*RN];
  __shared__ float sRowInv[TI*LN];
  __shared__ float sCapN[LN];
  __shared__ float sImgN[TI*RN];
  __shared__ float sEt[TI*LN];
  __shared__ float sEi[TI*RN];

  const int cl = blockIdx.y;
  const int c  = cbase + cl;
  const int it = blockIdx.x;
  const int tid = threadIdx.x;
  const int nw = cap_lens[c];
  const float nwf = (float)nw;

  for (int idx = tid; idx < LN*RT/4; idx += 256) {
    const int l = idx / 36, jseg = idx - l*36;
    const float4 v = *(const float4*)(dots + ((size_t)cl*LN + l)*NT + (size_t)it*RT + jseg*4);
    float* dst = &sDots[l][jseg*4];
    dst[0]=v.x; dst[1]=v.y; dst[2]=v.z; dst[3]=v.w;
  }
  for (int idx = tid; idx < TI*RN*48/4; idx += 256)
    ((float4*)sGi4)[idx] = make_float4(0.f,0.f,0.f,0.f);
  for (int idx = tid; idx < 576; idx += 256) {
    const int rw = idx/12, mq = idx - rw*12;
    *(float4*)&sGc[rw*48 + mq*4] = *(const float4*)(gC + (size_t)c*LN*LN + rw*LN + mq*4);
  }
  if (tid < LN) sCapN[tid] = nC[c*LN + tid];
  if (tid < TI*RN) sImgN[tid] = nI[it*TI*RN + tid];
  __syncthreads();

  for (int idx = tid; idx < TI*RN*RN; idx += 256) {
    const int i = idx / (RN*RN), rem = idx - i*(RN*RN);
    const int s = rem / RN, col = rem - s*RN;
    const int blk = col / 9, cib = col - blk*9;
    sGi4[(i*RN + s)*48 + blk*12 + cib] = gI[(size_t)(it*TI+i)*RN*RN + rem];
  }
  if (tid < TI*RN) {
    const int i = tid/RN, r = tid - i*RN;
    float s = 0.f;
    for (int l = 0; l < LN; ++l) { const float v = leaky(sDots[l][i*RN+r]); s += v*v; }
    sColInv[tid] = 1.f/(sqrtf(s) + EPSF);
  }
  if (tid < TI*LN) {
    const int i = tid/LN, l = tid - i*LN;
    float s = 0.f;
    for (int r = 0; r < RN; ++r) { const float v = leaky(sDots[l][i*RN+r]); s += v*v; }
    sRowInv[tid] = 1.f/(sqrtf(s) + EPSF);
  }
  __syncthreads();

  const int lane = tid & 63;
  const int iw   = tid >> 6;        // wave index = image slot
  const int tm   = lane >> 2;       // team 0..15 within wave
  const int q4   = lane & 3;

  // ===== t2i: wave iw, team tm rows l = tm+16*rr, lane owns 9 regions =====
  {
    float xt[3][12], w12t[3], invdt[3];
    const int cb = iw*RN + q4*9;
    #pragma unroll
    for (int rr = 0; rr < 3; ++rr) {
      const int l = tm + 16*rr;
      float d9[9];
      #pragma unroll
      for (int j = 0; j < 9; ++j) d9[j] = sDots[l][cb + j];
      float m = -1e30f;
      #pragma unroll
      for (int j = 0; j < 9; ++j) {
        const float v = leaky(d9[j]) * sColInv[cb + j] * LSM;
        xt[rr][j] = v; m = fmaxf(m, v);
      }
      m = fmaxf(m, __shfl_xor(m, 1, 4));
      m = fmaxf(m, __shfl_xor(m, 2, 4));
      float se = 0.f;
      #pragma unroll
      for (int j = 0; j < 9; ++j) { const float e = __expf(xt[rr][j] - m); xt[rr][j] = e; se += e; }
      xt[rr][9] = xt[rr][10] = xt[rr][11] = 0.f;
      se += __shfl_xor(se, 1, 4); se += __shfl_xor(se, 2, 4);
      const float inv = __builtin_amdgcn_rcpf(se);
      float s = 0.f;
      #pragma unroll
      for (int j = 0; j < 9; ++j) { const float p = xt[rr][j]*inv; xt[rr][j] = p; s += p; }
      s += __shfl_xor(s, 1, 4); s += __shfl_xor(s, 2, 4);
      float ts = 0.f;
      #pragma unroll
      for (int j = 0; j < 9; ++j) {
        const float t = (xt[rr][j]*36.f - s > 0.f) ? xt[rr][j] : 0.f;
        xt[rr][j] = t; ts += t;
      }
      ts += __shfl_xor(ts, 1, 4); ts += __shfl_xor(ts, 2, 4);
      const float den = (ts > 0.f) ? ts : 1.f;
      invdt[rr] = __builtin_amdgcn_rcpf(den);
      float w = 0.f;
      #pragma unroll
      for (int j = 0; j < 9; ++j) w += xt[rr][j]*d9[j];
      w += __shfl_xor(w, 1, 4); w += __shfl_xor(w, 2, 4);
      w12t[rr] = w;
    }
    float qqt[3] = {0.f, 0.f, 0.f};
    const float* giB = sGi4 + (size_t)iw*RN*48 + q4*12;
    #pragma unroll
    for (int sl = 0; sl < 4; ++sl)
      #pragma unroll
      for (int si = 0; si < 9; ++si) {
        const float4* gr = (const float4*)(giB + (sl*9 + si)*48);
        const float4 g0 = gr[0], g1 = gr[1], g2 = gr[2];
        #pragma unroll
        for (int rr = 0; rr < 3; ++rr) {
          const float tv = __shfl(xt[rr][si], sl, 4);
          const float p =
            xt[rr][0]*g0.x + xt[rr][1]*g0.y + xt[rr][2]*g0.z + xt[rr][3]*g0.w +
            xt[rr][4]*g1.x + xt[rr][5]*g1.y + xt[rr][6]*g1.z + xt[rr][7]*g1.w +
            xt[rr][8]*g2.x;
          qqt[rr] += tv * p;
        }
      }
    #pragma unroll
    for (int rr = 0; rr < 3; ++rr) {
      float qq = qqt[rr];
      qq += __shfl_xor(qq, 1, 4); qq += __shfl_xor(qq, 2, 4);
      if (q4 == 0) {
        const int l = tm + 16*rr;
        const float w2 = sqrtf(fmaxf(qq*invdt[rr]*invdt[rr], 1e-16f));
        const float sim = (w12t[rr]*invdt[rr]) *
                          __builtin_amdgcn_rcpf(fmaxf(sCapN[l]*w2, EPSF));
        sEt[iw*LN + l] = (l < nw) ? __expf(LLSE*sim) : 0.f;
      }
    }
  }

  // ===== i2t: wave iw, team tm rows r = tm+16*rr (r<36 valid), lane owns 12 words =====
  {
    float xi[3][12], w12i[3], invdi[3];
    #pragma unroll
    for (int rr = 0; rr < 3; ++rr) {
      const int r = tm + 16*rr;
      const bool ok = (r < RN);
      float d12[12];
      #pragma unroll
      for (int j = 0; j < 12; ++j) d12[j] = ok ? sDots[q4*12 + j][iw*RN + r] : 0.f;
      float m = -1e30f;
      #pragma unroll
      for (int j = 0; j < 12; ++j) {
        const int l = q4*12 + j;
        const float v = (l < nw) ? leaky(d12[j]) * sRowInv[iw*LN + l] * LSM : -1e9f;
        xi[rr][j] = v; m = fmaxf(m, v);
      }
      m = fmaxf(m, __shfl_xor(m, 1, 4));
      m = fmaxf(m, __shfl_xor(m, 2, 4));
      float se = 0.f;
      #pragma unroll
      for (int j = 0; j < 12; ++j) { const float e = __expf(xi[rr][j] - m); xi[rr][j] = e; se += e; }
      se += __shfl_xor(se, 1, 4); se += __shfl_xor(se, 2, 4);
      const float inv = __builtin_amdgcn_rcpf(se);
      float s = 0.f;
      #pragma unroll
      for (int j = 0; j < 12; ++j) { const float p = xi[rr][j]*inv; xi[rr][j] = p; s += p; }
      s += __shfl_xor(s, 1, 4); s += __shfl_xor(s, 2, 4);
      float ts = 0.f;
      #pragma unroll
      for (int j = 0; j < 12; ++j) {
        const float t = (xi[rr][j]*nwf - s > 0.f) ? xi[rr][j] : 0.f;
        xi[rr][j] = t; ts += t;
      }
      ts += __shfl_xor(ts, 1, 4); ts += __shfl_xor(ts, 2, 4);
      const float den = (ts > 0.f) ? ts : 1.f;
      invdi[rr] = __builtin_amdgcn_rcpf(den);
      float w = 0.f;
      #pragma unroll
      for (int j = 0; j < 12; ++j) w += xi[rr][j]*d12[j];
      w += __shfl_xor(w, 1, 4); w += __shfl_xor(w, 2, 4);
      w12i[rr] = w;
    }
    float qqi[3] = {0.f, 0.f, 0.f};
    const float* gcB = sGc + q4*12;
    #pragma unroll
    for (int sl = 0; sl < 4; ++sl)
      #pragma unroll
      for (int si = 0; si < 12; ++si) {
        const float4* gr = (const float4*)(gcB + (sl*12 + si)*48);
        const float4 g0 = gr[0], g1 = gr[1], g2 = gr[2];
        #pragma unroll
        for (int rr = 0; rr < 3; ++rr) {
          const float tv = __shfl(xi[rr][si], sl, 4);
          const float p =
            xi[rr][0]*g0.x + xi[rr][1]*g0.y + xi[rr][2]*g0.z + xi[rr][3]*g0.w +
            xi[rr][4]*g1.x + xi[rr][5]*g1.y + xi[rr][6]*g1.z + xi[rr][7]*g1.w +
            xi[rr][8]*g2.x + xi[rr][9]*g2.y + xi[rr][10]*g2.z + xi[rr][11]*g2.w;
          qqi[rr] += tv * p;
        }
      }
    #pragma unroll
    for (int rr = 0; rr < 3; ++rr) {
      float qq = qqi[rr];
      qq += __shfl_xor(qq, 1, 4); qq += __shfl_xor(qq, 2, 4);
      const int r = tm + 16*rr;
      if (q4 == 0 && r < RN) {
        const float w2 = sqrtf(fmaxf(qq*invdi[rr]*invdi[rr], 1e-16f));
        const float sim = (w12i[rr]*invdi[rr]) *
                          __builtin_amdgcn_rcpf(fmaxf(sImgN[iw*RN + r]*w2, EPSF));
        sEi[iw*RN + r] = __expf(LLSE*sim);
      }
    }
  }
  __syncthreads();
  if (tid < TI) {
    float st = 0.f, si2 = 0.f;
    for (int l = 0; l < LN; ++l) st += sEt[tid*LN + l];
    for (int r = 0; r < RN; ++r) si2 += sEi[tid*RN + r];
    scores[(size_t)(it*TI + tid)*CN + c] = __logf(st)/LLSE + __logf(si2)/LLSE;
  }
}

// ---------------- Kernel 4: margin ranking loss ----------------
__global__ __launch_bounds__(128) void loss_kernel(
    const float* __restrict__ S, float* __restrict__ out)
{
  __shared__ float red[128];
  const int t = threadIdx.x;
  const float d = S[t*CN + t];
  float m1 = -1e30f, m2 = -1e30f;
  for (int cc = 0; cc < CN; ++cc)
    if (cc != t) m1 = fmaxf(m1, 0.2f + S[t*CN+cc] - d);
  for (int i2 = 0; i2 < INN; ++i2)
    if (i2 != t) m2 = fmaxf(m2, 0.2f + S[i2*CN+t] - d);
  red[t] = fmaxf(m1, 0.f) + fmaxf(m2, 0.f);
  __syncthreads();
  for (int s = 64; s > 0; s >>= 1) {
    if (t < s) red[t] += red[t+s];
    __syncthreads();
  }
  if (t == 0) out[0] = red[0];
}

extern "C" void kernel_launch(void* const* d_in, const int* in_sizes, int n_in,
                              void* d_out, int out_size, void* d_ws, size_t ws_size,
                              hipStream_t stream) {
  (void)in_sizes; (void)n_in; (void)out_size;
  const float* imgs = (const float*)d_in[0];
  const float* caps = (const float*)d_in[1];
  const int*   lens = (const int*)d_in[2];

  const size_t bfUS = 2*((size_t)MT + NT)*DN;
  const size_t smallF = (size_t)INN*RN*RN + INN*RN + (size_t)CN*LN*LN + CN*LN + (size_t)INN*CN;
  int g = CN;
  while (g > 8) {
    const size_t need = bfUS*2 + (smallF + (size_t)g*LN*NT)*4;
    if (need <= ws_size) break;
    g >>= 1;
  }

  ushort* aHi = (ushort*)d_ws;
  ushort* aLo = aHi + (size_t)MT*DN;
  ushort* bHi = aLo + (size_t)MT*DN;
  ushort* bLo = bHi + (size_t)NT*DN;
  float* fbase = (float*)(bLo + (size_t)NT*DN);
  float* gI     = fbase;
  float* nI     = gI + (size_t)INN*RN*RN;
  float* gC     = nI + (size_t)INN*RN;
  float* nC     = gC + (size_t)CN*LN*LN;
  float* scores = nC + (size_t)CN*LN;
  float* dots   = scores + (size_t)INN*CN;

  conv_kernel<<<dim3(1024), dim3(256), 0, stream>>>(caps, imgs, aHi, aLo, bHi, bLo);
  gram_kernel<<<dim3(INN+CN), dim3(256), 0, stream>>>(imgs, caps, gI, nI, gC, nC);
  for (int c0 = 0; c0 < CN; c0 += g) {
    dots_gemm_mfma<<<dim3(NT/128, g*LN/128), dim3(256), 0, stream>>>(
        aHi, aLo, bHi, bLo, dots, c0*LN);
    attn_kernel<<<dim3(INN/TI, g), dim3(256), 0, stream>>>(
        dots, lens, gI, nI, gC, nC, scores, c0);
  }
  loss_kernel<<<dim3(1), dim3(128), 0, stream>>>(scores, (float*)d_out);
}

// Round 9
// 517.165 us; speedup vs baseline: 2.6515x; 2.6515x over previous
//
#include <hip/hip_runtime.h>
#include <math.h>

#define CN 128   // captions
#define INN 128  // images
#define LN 48    // words
#define RN 36    // regions
#define DN 1024  // feature dim
#define TI 4     // images per attn block tile
#define RT 144   // TI*RN
#define MT 6144  // CN*LN
#define NT 4608  // INN*RN
#define EPSF 1e-8f
#define LSM 9.0f
#define LLSE 6.0f

__device__ __forceinline__ float leaky(float x){ return x > 0.f ? x : 0.1f*x; }
__device__ __forceinline__ float dot4(float4 a, float4 b){
  return a.x*b.x + a.y*b.y + a.z*b.z + a.w*b.w;
}

typedef const __attribute__((address_space(1))) unsigned int* gp_t;
typedef __attribute__((address_space(3))) unsigned int* lp_t;
__device__ __forceinline__ void gload16u(const ushort* g, ushort* l) {
  __builtin_amdgcn_global_load_lds((gp_t)g, (lp_t)l, 16, 0, 0);
}

typedef short s16x8 __attribute__((ext_vector_type(8)));
typedef float f32x4 __attribute__((ext_vector_type(4)));

// ---------------- Kernel 0: fp32 -> bf16 hi/lo split (RNE) ----------------
__global__ __launch_bounds__(256) void conv_kernel(
    const float* __restrict__ caps, const float* __restrict__ imgs,
    ushort* __restrict__ aHi, ushort* __restrict__ aLo,
    ushort* __restrict__ bHi, ushort* __restrict__ bLo)
{
  const int NA = MT*DN/4, NB = NT*DN/4;
  for (int i = blockIdx.x*256 + threadIdx.x; i < NA + NB; i += gridDim.x*256) {
    const float4 v = (i < NA) ? ((const float4*)caps)[i] : ((const float4*)imgs)[i - NA];
    const float fv[4] = {v.x, v.y, v.z, v.w};
    ushort hh[4], ll[4];
    #pragma unroll
    for (int e = 0; e < 4; ++e) {
      const unsigned u = __float_as_uint(fv[e]);
      const ushort hi = (ushort)((u + 0x7fffu + ((u>>16)&1u)) >> 16);
      const float res = fv[e] - __uint_as_float((unsigned)hi << 16);
      const unsigned u2 = __float_as_uint(res);
      hh[e] = hi;
      ll[e] = (ushort)((u2 + 0x7fffu + ((u2>>16)&1u)) >> 16);
    }
    const ushort4 h = make_ushort4(hh[0],hh[1],hh[2],hh[3]);
    const ushort4 lo = make_ushort4(ll[0],ll[1],ll[2],ll[3]);
    if (i < NA) { ((ushort4*)aHi)[i] = h;    ((ushort4*)aLo)[i] = lo; }
    else        { ((ushort4*)bHi)[i-NA] = h; ((ushort4*)bLo)[i-NA] = lo; }
  }
}

// ---------------- Kernel 1: Gram matrices + norms (fp32, LDS D-tiled) ----------------
__global__ __launch_bounds__(256) void gram_kernel(
    const float* __restrict__ imgs, const float* __restrict__ caps,
    float* __restrict__ gI, float* __restrict__ nI,
    float* __restrict__ gC, float* __restrict__ nC)
{
  __shared__ __align__(16) float L[LN*132];   // max 48 rows x 132
  const int b = blockIdx.x, tid = threadIdx.x;
  if (b < INN) {
    const float* base = imgs + (size_t)b*RN*DN;
    const int rg = tid/12, cg = tid - (tid/12)*12;   // 18x12 teams, 216 active
    const bool active = tid < 216;
    float a[2][3];
    #pragma unroll
    for (int u = 0; u < 2; ++u)
      #pragma unroll
      for (int v = 0; v < 3; ++v) a[u][v] = 0.f;
    for (int d0 = 0; d0 < DN; d0 += 128) {
      __syncthreads();
      for (int idx = tid; idx < RN*32; idx += 256) {
        const int row = idx >> 5, ch = idx & 31;
        *(float4*)&L[row*132 + ch*4] = *(const float4*)(base + row*DN + d0 + ch*4);
      }
      __syncthreads();
      if (active) {
        const float* r0 = &L[(2*rg)*132],   * r1 = &L[(2*rg+1)*132];
        const float* c0 = &L[(3*cg)*132],   * c1 = &L[(3*cg+1)*132], * c2 = &L[(3*cg+2)*132];
        #pragma unroll
        for (int k = 0; k < 32; ++k) {
          const float4 x0 = *(const float4*)(r0 + k*4);
          const float4 x1 = *(const float4*)(r1 + k*4);
          const float4 y0 = *(const float4*)(c0 + k*4);
          const float4 y1 = *(const float4*)(c1 + k*4);
          const float4 y2 = *(const float4*)(c2 + k*4);
          a[0][0] += dot4(x0,y0); a[0][1] += dot4(x0,y1); a[0][2] += dot4(x0,y2);
          a[1][0] += dot4(x1,y0); a[1][1] += dot4(x1,y1); a[1][2] += dot4(x1,y2);
        }
      }
    }
    if (active) {
      float* gb = gI + (size_t)b*RN*RN;
      #pragma unroll
      for (int u = 0; u < 2; ++u)
        #pragma unroll
        for (int v = 0; v < 3; ++v) {
          const int r = 2*rg + u, s = 3*cg + v;
          gb[r*RN + s] = a[u][v];
          if (r == s) nI[b*RN + r] = sqrtf(fmaxf(a[u][v], 1e-16f));
        }
    }
  } else {
    const int c = b - INN;
    const float* base = caps + (size_t)c*LN*DN;
    const int rg = tid >> 4, cg = tid & 15;          // 16x16 teams, all 256 active
    float a[3][3];
    #pragma unroll
    for (int u = 0; u < 3; ++u)
      #pragma unroll
      for (int v = 0; v < 3; ++v) a[u][v] = 0.f;
    for (int d0 = 0; d0 < DN; d0 += 128) {
      __syncthreads();
      for (int idx = tid; idx < LN*32; idx += 256) {
        const int row = idx >> 5, ch = idx & 31;
        *(float4*)&L[row*132 + ch*4] = *(const float4*)(base + row*DN + d0 + ch*4);
      }
      __syncthreads();
      const float* r0 = &L[(3*rg)*132],   * r1 = &L[(3*rg+1)*132], * r2 = &L[(3*rg+2)*132];
      const float* c0 = &L[(3*cg)*132],   * c1 = &L[(3*cg+1)*132], * c2 = &L[(3*cg+2)*132];
      #pragma unroll
      for (int k = 0; k < 32; ++k) {
        const float4 x0 = *(const float4*)(r0 + k*4);
        const float4 x1 = *(const float4*)(r1 + k*4);
        const float4 x2 = *(const float4*)(r2 + k*4);
        const float4 y0 = *(const float4*)(c0 + k*4);
        const float4 y1 = *(const float4*)(c1 + k*4);
        const float4 y2 = *(const float4*)(c2 + k*4);
        a[0][0] += dot4(x0,y0); a[0][1] += dot4(x0,y1); a[0][2] += dot4(x0,y2);
        a[1][0] += dot4(x1,y0); a[1][1] += dot4(x1,y1); a[1][2] += dot4(x1,y2);
        a[2][0] += dot4(x2,y0); a[2][1] += dot4(x2,y1); a[2][2] += dot4(x2,y2);
      }
    }
    float* gb = gC + (size_t)c*LN*LN;
    #pragma unroll
    for (int u = 0; u < 3; ++u)
      #pragma unroll
      for (int v = 0; v < 3; ++v) {
        const int r = 3*rg + u, s = 3*cg + v;
        gb[r*LN + s] = a[u][v];
        if (r == s) nC[c*LN + r] = sqrtf(fmaxf(a[u][v], 1e-16f));
      }
  }
}

// ---------------- Kernel 2: dots GEMM via bf16x3 MFMA ----------------
__global__ __launch_bounds__(256) void dots_gemm_mfma(
    const ushort* __restrict__ aHi, const ushort* __restrict__ aLo,
    const ushort* __restrict__ bHi, const ushort* __restrict__ bLo,
    float* __restrict__ dots, int arow0)
{
  __shared__ __align__(16) ushort sT[16384];   // Ah Al Bh Bl, 8KB each
  const int tid = threadIdx.x;
  const int wv = tid >> 6, lane = tid & 63;
  const int l15 = lane & 15, kg = lane >> 4;
  const int wr = wv >> 1, wc = wv & 1;
  const int M0 = blockIdx.y * 128;
  const int N0 = blockIdx.x * 128;

  int offA[4], offB[4];
  #pragma unroll
  for (int f = 0; f < 4; ++f) {
    const int rA = wr*64 + f*16 + l15;
    offA[f] = rA*32 + ((kg ^ ((rA>>1)&3)) << 3);
    const int rB = wc*64 + f*16 + l15;
    offB[f] = rB*32 + ((kg ^ ((rB>>1)&3)) << 3);
  }
  int srow[2], sgk[2]; unsigned dOff[2];
  #pragma unroll
  for (int h = 0; h < 2; ++h) {
    const int ch = h*256 + wv*64 + lane;
    const int row = ch >> 2, gp = ch & 3;
    srow[h] = row;
    sgk[h] = (gp ^ ((row>>1)&3)) * 8;
    dOff[h] = (unsigned)(h*256 + wv*64) * 8;
  }

  f32x4 acc[4][4];
  #pragma unroll
  for (int mf = 0; mf < 4; ++mf)
    #pragma unroll
    for (int nf = 0; nf < 4; ++nf) acc[mf][nf] = (f32x4){0.f,0.f,0.f,0.f};

  const size_t aR = (size_t)(arow0 + M0);
  for (int k0 = 0; k0 < DN; k0 += 32) {
    __syncthreads();
    #pragma unroll
    for (int h = 0; h < 2; ++h) {
      const size_t ao = (aR + srow[h])*DN + k0 + sgk[h];
      const size_t bo = ((size_t)(N0 + srow[h]))*DN + k0 + sgk[h];
      gload16u(aHi + ao, sT + dOff[h]);
      gload16u(aLo + ao, sT + 4096 + dOff[h]);
      gload16u(bHi + bo, sT + 8192 + dOff[h]);
      gload16u(bLo + bo, sT + 12288 + dOff[h]);
    }
    asm volatile("s_waitcnt vmcnt(0)" ::: "memory");
    __syncthreads();
    s16x8 ah[4], al[4], bh[4], bl[4];
    #pragma unroll
    for (int f = 0; f < 4; ++f) {
      ah[f] = *(const s16x8*)&sT[offA[f]];
      al[f] = *(const s16x8*)&sT[4096 + offA[f]];
      bh[f] = *(const s16x8*)&sT[8192 + offB[f]];
      bl[f] = *(const s16x8*)&sT[12288 + offB[f]];
    }
    #pragma unroll
    for (int mf = 0; mf < 4; ++mf)
      #pragma unroll
      for (int nf = 0; nf < 4; ++nf) {
        acc[mf][nf] = __builtin_amdgcn_mfma_f32_16x16x32_bf16(ah[mf], bh[nf], acc[mf][nf], 0,0,0);
        acc[mf][nf] = __builtin_amdgcn_mfma_f32_16x16x32_bf16(ah[mf], bl[nf], acc[mf][nf], 0,0,0);
        acc[mf][nf] = __builtin_amdgcn_mfma_f32_16x16x32_bf16(al[mf], bh[nf], acc[mf][nf], 0,0,0);
      }
  }
  #pragma unroll
  for (int mf = 0; mf < 4; ++mf)
    #pragma unroll
    for (int nf = 0; nf < 4; ++nf) {
      const int n = N0 + wc*64 + nf*16 + l15;
      #pragma unroll
      for (int r = 0; r < 4; ++r) {
        const int m = M0 + wr*64 + mf*16 + kg*4 + r;
        dots[(size_t)m*NT + n] = acc[mf][nf][r];
      }
    }
}

// ---------------- Kernel 3: attention + scores ----------------
// R7 structure (one row per 4-lane team, 88 VGPR, no spills) + fast-math only.
// R8 lesson: 3-row register batching (72 live floats through 108-iter unrolled
// qq loop) spilled to 256 VGPR / 1.8 GB scratch churn. Do NOT re-batch.
__global__ __launch_bounds__(256) void attn_kernel(
    const float* __restrict__ dots, const int* __restrict__ cap_lens,
    const float* __restrict__ gI, const float* __restrict__ nI,
    const float* __restrict__ gC, const float* __restrict__ nC,
    float* __restrict__ scores, int cbase)
{
  __shared__ float sDots[LN][RT+1];
  __shared__ __align__(16) float sGi4[TI*RN*48];
  __shared__ __align__(16) float sGc[LN*48];
  __shared__ float sColInv[TI*RN];
  __shared__ float sRowInv[TI*LN];
  __shared__ float sCapN[LN];
  __shared__ float sImgN[TI*RN];
  __shared__ float sEt[TI*LN];
  __shared__ float sEi[TI*RN];

  const int cl = blockIdx.y;
  const int c  = cbase + cl;
  const int it = blockIdx.x;
  const int tid = threadIdx.x;
  const int nw = cap_lens[c];
  const float nwf = (float)nw;

  for (int idx = tid; idx < LN*RT/4; idx += 256) {
    const int l = idx / 36, jseg = idx - l*36;
    const float4 v = *(const float4*)(dots + ((size_t)cl*LN + l)*NT + (size_t)it*RT + jseg*4);
    float* dst = &sDots[l][jseg*4];
    dst[0]=v.x; dst[1]=v.y; dst[2]=v.z; dst[3]=v.w;
  }
  for (int idx = tid; idx < TI*RN*48/4; idx += 256)
    ((float4*)sGi4)[idx] = make_float4(0.f,0.f,0.f,0.f);
  for (int idx = tid; idx < 576; idx += 256) {
    const int rw = idx/12, mq = idx - rw*12;
    *(float4*)&sGc[rw*48 + mq*4] = *(const float4*)(gC + (size_t)c*LN*LN + rw*LN + mq*4);
  }
  if (tid < LN) sCapN[tid] = nC[c*LN + tid];
  if (tid < TI*RN) sImgN[tid] = nI[it*TI*RN + tid];
  __syncthreads();

  for (int idx = tid; idx < TI*RN*RN; idx += 256) {
    const int i = idx / (RN*RN), rem = idx - i*(RN*RN);
    const int s = rem / RN, col = rem - s*RN;
    const int blk = col / 9, cib = col - blk*9;
    sGi4[(i*RN + s)*48 + blk*12 + cib] = gI[(size_t)(it*TI+i)*RN*RN + rem];
  }
  if (tid < TI*RN) {
    const int i = tid/RN, r = tid - i*RN;
    float s = 0.f;
    for (int l = 0; l < LN; ++l) { const float v = leaky(sDots[l][i*RN+r]); s += v*v; }
    sColInv[tid] = __builtin_amdgcn_rcpf(sqrtf(s) + EPSF);
  }
  if (tid < TI*LN) {
    const int i = tid/LN, l = tid - i*LN;
    float s = 0.f;
    for (int r = 0; r < RN; ++r) { const float v = leaky(sDots[l][i*RN+r]); s += v*v; }
    sRowInv[tid] = __builtin_amdgcn_rcpf(sqrtf(s) + EPSF);
  }
  __syncthreads();

  const int team = tid >> 2, q4 = tid & 3;

  // ===== t2i: 192 rows (i*48+l), lane owns 9 regions (padded to 12) =====
  #pragma unroll 1
  for (int pass = 0; pass < 3; ++pass) {
    const int rowid = pass*64 + team;
    const int i = rowid / LN, l = rowid - i*LN;
    const int cb = i*RN + q4*9;
    float d9[9], x12[12];
    #pragma unroll
    for (int j = 0; j < 9; ++j) d9[j] = sDots[l][cb + j];
    float m = -1e30f;
    #pragma unroll
    for (int j = 0; j < 9; ++j) {
      const float v = leaky(d9[j]) * sColInv[cb + j] * LSM;
      x12[j] = v; m = fmaxf(m, v);
    }
    m = fmaxf(m, __shfl_xor(m, 1, 4));
    m = fmaxf(m, __shfl_xor(m, 2, 4));
    float se = 0.f;
    #pragma unroll
    for (int j = 0; j < 9; ++j) { const float e = __expf(x12[j] - m); x12[j] = e; se += e; }
    x12[9] = x12[10] = x12[11] = 0.f;
    se += __shfl_xor(se, 1, 4); se += __shfl_xor(se, 2, 4);
    const float inv = __builtin_amdgcn_rcpf(se);
    float s = 0.f;
    #pragma unroll
    for (int j = 0; j < 9; ++j) { const float p = x12[j]*inv; x12[j] = p; s += p; }
    s += __shfl_xor(s, 1, 4); s += __shfl_xor(s, 2, 4);
    float ts = 0.f;
    #pragma unroll
    for (int j = 0; j < 9; ++j) {
      const float tv = (x12[j]*36.f - s > 0.f) ? x12[j] : 0.f;
      x12[j] = tv; ts += tv;
    }
    ts += __shfl_xor(ts, 1, 4); ts += __shfl_xor(ts, 2, 4);
    const float den = (ts > 0.f) ? ts : 1.f;
    const float invd = __builtin_amdgcn_rcpf(den);
    float w12 = 0.f;
    #pragma unroll
    for (int j = 0; j < 9; ++j) w12 += x12[j]*d9[j];
    w12 += __shfl_xor(w12, 1, 4); w12 += __shfl_xor(w12, 2, 4);
    float qq = 0.f;
    const float* giB = sGi4 + (size_t)i*RN*48 + q4*12;
    #pragma unroll
    for (int sl = 0; sl < 4; ++sl) {
      #pragma unroll
      for (int si = 0; si < 9; ++si) {
        const float tv = __shfl(x12[si], sl, 4);
        const float4* gr = (const float4*)(giB + (sl*9 + si)*48);
        const float4 g0 = gr[0], g1 = gr[1], g2 = gr[2];
        const float p =
          x12[0]*g0.x + x12[1]*g0.y + x12[2]*g0.z + x12[3]*g0.w +
          x12[4]*g1.x + x12[5]*g1.y + x12[6]*g1.z + x12[7]*g1.w +
          x12[8]*g2.x + x12[9]*g2.y + x12[10]*g2.z + x12[11]*g2.w;
        qq += tv * p;
      }
    }
    qq += __shfl_xor(qq, 1, 4); qq += __shfl_xor(qq, 2, 4);
    if (q4 == 0) {
      const float w2 = sqrtf(fmaxf(qq*invd*invd, 1e-16f));
      const float sim = (w12*invd) * __builtin_amdgcn_rcpf(fmaxf(sCapN[l]*w2, EPSF));
      sEt[rowid] = (l < nw) ? __expf(LLSE*sim) : 0.f;
    }
  }

  // ===== i2t: 144 rows (i*36+r), lane owns 12 words =====
  #pragma unroll 1
  for (int pass = 0; pass < 3; ++pass) {
    const int rowid = pass*64 + team;
    if (rowid < TI*RN) {
      const int i = rowid / RN, r = rowid - i*RN;
      float d12[12], x12[12];
      #pragma unroll
      for (int j = 0; j < 12; ++j) d12[j] = sDots[q4*12+j][i*RN + r];
      float m = -1e30f;
      #pragma unroll
      for (int j = 0; j < 12; ++j) {
        const int l = q4*12 + j;
        const float v = (l < nw) ? leaky(d12[j]) * sRowInv[i*LN + l] * LSM : -1e9f;
        x12[j] = v; m = fmaxf(m, v);
      }
      m = fmaxf(m, __shfl_xor(m, 1, 4));
      m = fmaxf(m, __shfl_xor(m, 2, 4));
      float se = 0.f;
      #pragma unroll
      for (int j = 0; j < 12; ++j) { const float e = __expf(x12[j] - m); x12[j] = e; se += e; }
      se += __shfl_xor(se, 1, 4); se += __shfl_xor(se, 2, 4);
      const float inv = __builtin_amdgcn_rcpf(se);
      float s = 0.f;
      #pragma unroll
      for (int j = 0; j < 12; ++j) { const float p = x12[j]*inv; x12[j] = p; s += p; }
      s += __shfl_xor(s, 1, 4); s += __shfl_xor(s, 2, 4);
      float ts = 0.f;
      #pragma unroll
      for (int j = 0; j < 12; ++j) {
        const float tv = (x12[j]*nwf - s > 0.f) ? x12[j] : 0.f;
        x12[j] = tv; ts += tv;
      }
      ts += __shfl_xor(ts, 1, 4); ts += __shfl_xor(ts, 2, 4);
      const float den = (ts > 0.f) ? ts : 1.f;
      const float invd = __builtin_amdgcn_rcpf(den);
      float w12 = 0.f;
      #pragma unroll
      for (int j = 0; j < 12; ++j) w12 += x12[j]*d12[j];
      w12 += __shfl_xor(w12, 1, 4); w12 += __shfl_xor(w12, 2, 4);
      float qq = 0.f;
      const float* gcB = sGc + q4*12;
      #pragma unroll
      for (int sl = 0; sl < 4; ++sl) {
        #pragma unroll
        for (int si = 0; si < 12; ++si) {
          const float tv = __shfl(x12[si], sl, 4);
          const float4* gr = (const float4*)(gcB + (sl*12 + si)*48);
          const float4 g0 = gr[0], g1 = gr[1], g2 = gr[2];
          const float p =
            x12[0]*g0.x + x12[1]*g0.y + x12[2]*g0.z + x12[3]*g0.w +
            x12[4]*g1.x + x12[5]*g1.y + x12[6]*g1.z + x12[7]*g1.w +
            x12[8]*g2.x + x12[9]*g2.y + x12[10]*g2.z + x12[11]*g2.w;
          qq += tv * p;
        }
      }
      qq += __shfl_xor(qq, 1, 4); qq += __shfl_xor(qq, 2, 4);
      if (q4 == 0) {
        const float w2 = sqrtf(fmaxf(qq*invd*invd, 1e-16f));
        const float sim = (w12*invd) * __builtin_amdgcn_rcpf(fmaxf(sImgN[rowid]*w2, EPSF));
        sEi[rowid] = __expf(LLSE*sim);
      }
    }
  }
  __syncthreads();
  if (tid < TI) {
    float st = 0.f, si2 = 0.f;
    for (int l = 0; l < LN; ++l) st += sEt[tid*LN + l];
    for (int r = 0; r < RN; ++r) si2 += sEi[tid*RN + r];
    scores[(size_t)(it*TI + tid)*CN + c] = __logf(st)/LLSE + __logf(si2)/LLSE;
  }
}

// ---------------- Kernel 4: margin ranking loss ----------------
__global__ __launch_bounds__(128) void loss_kernel(
    const float* __restrict__ S, float* __restrict__ out)
{
  __shared__ float red[128];
  const int t = threadIdx.x;
  const float d = S[t*CN + t];
  float m1 = -1e30f, m2 = -1e30f;
  for (int cc = 0; cc < CN; ++cc)
    if (cc != t) m1 = fmaxf(m1, 0.2f + S[t*CN+cc] - d);
  for (int i2 = 0; i2 < INN; ++i2)
    if (i2 != t) m2 = fmaxf(m2, 0.2f + S[i2*CN+t] - d);
  red[t] = fmaxf(m1, 0.f) + fmaxf(m2, 0.f);
  __syncthreads();
  for (int s = 64; s > 0; s >>= 1) {
    if (t < s) red[t] += red[t+s];
    __syncthreads();
  }
  if (t == 0) out[0] = red[0];
}

extern "C" void kernel_launch(void* const* d_in, const int* in_sizes, int n_in,
                              void* d_out, int out_size, void* d_ws, size_t ws_size,
                              hipStream_t stream) {
  (void)in_sizes; (void)n_in; (void)out_size;
  const float* imgs = (const float*)d_in[0];
  const float* caps = (const float*)d_in[1];
  const int*   lens = (const int*)d_in[2];

  const size_t bfUS = 2*((size_t)MT + NT)*DN;
  const size_t smallF = (size_t)INN*RN*RN + INN*RN + (size_t)CN*LN*LN + CN*LN + (size_t)INN*CN;
  int g = CN;
  while (g > 8) {
    const size_t need = bfUS*2 + (smallF + (size_t)g*LN*NT)*4;
    if (need <= ws_size) break;
    g >>= 1;
  }

  ushort* aHi = (ushort*)d_ws;
  ushort* aLo = aHi + (size_t)MT*DN;
  ushort* bHi = aLo + (size_t)MT*DN;
  ushort* bLo = bHi + (size_t)NT*DN;
  float* fbase = (float*)(bLo + (size_t)NT*DN);
  float* gI     = fbase;
  float* nI     = gI + (size_t)INN*RN*RN;
  float* gC     = nI + (size_t)INN*RN;
  float* nC     = gC + (size_t)CN*LN*LN;
  float* scores = nC + (size_t)CN*LN;
  float* dots   = scores + (size_t)INN*CN;

  conv_kernel<<<dim3(1024), dim3(256), 0, stream>>>(caps, imgs, aHi, aLo, bHi, bLo);
  gram_kernel<<<dim3(INN+CN), dim3(256), 0, stream>>>(imgs, caps, gI, nI, gC, nC);
  for (int c0 = 0; c0 < CN; c0 += g) {
    dots_gemm_mfma<<<dim3(NT/128, g*LN/128), dim3(256), 0, stream>>>(
        aHi, aLo, bHi, bLo, dots, c0*LN);
    attn_kernel<<<dim3(INN/TI, g), dim3(256), 0, stream>>>(
        dots, lens, gI, nI, gC, nC, scores, c0);
  }
  loss_kernel<<<dim3(1), dim3(128), 0, stream>>>(scores, (float*)d_out);
}

// Round 10
// 459.950 us; speedup vs baseline: 2.9813x; 1.1244x over previous
//
#include <hip/hip_runtime.h>
#include <math.h>

#define CN 128   // captions
#define INN 128  // images
#define LN 48    // words
#define RN 36    // regions
#define DN 1024  // feature dim
#define TI 4     // images per gemm-M-tile grouping (unchanged)
#define TIA 2    // images per attn block (R10: halved for occupancy 2->3 blocks/CU)
#define RTA (TIA*RN)   // 72
#define MT 6144  // CN*LN
#define NT 4608  // INN*RN
#define EPSF 1e-8f
#define LSM 9.0f
#define LLSE 6.0f

__device__ __forceinline__ float leaky(float x){ return x > 0.f ? x : 0.1f*x; }
__device__ __forceinline__ float dot4(float4 a, float4 b){
  return a.x*b.x + a.y*b.y + a.z*b.z + a.w*b.w;
}

typedef const __attribute__((address_space(1))) unsigned int* gp_t;
typedef __attribute__((address_space(3))) unsigned int* lp_t;
__device__ __forceinline__ void gload16u(const ushort* g, ushort* l) {
  __builtin_amdgcn_global_load_lds((gp_t)g, (lp_t)l, 16, 0, 0);
}

typedef short s16x8 __attribute__((ext_vector_type(8)));
typedef float f32x4 __attribute__((ext_vector_type(4)));

// ---------------- Kernel 0: fp32 -> bf16 hi/lo split (RNE) ----------------
__global__ __launch_bounds__(256) void conv_kernel(
    const float* __restrict__ caps, const float* __restrict__ imgs,
    ushort* __restrict__ aHi, ushort* __restrict__ aLo,
    ushort* __restrict__ bHi, ushort* __restrict__ bLo)
{
  const int NA = MT*DN/4, NB = NT*DN/4;
  for (int i = blockIdx.x*256 + threadIdx.x; i < NA + NB; i += gridDim.x*256) {
    const float4 v = (i < NA) ? ((const float4*)caps)[i] : ((const float4*)imgs)[i - NA];
    const float fv[4] = {v.x, v.y, v.z, v.w};
    ushort hh[4], ll[4];
    #pragma unroll
    for (int e = 0; e < 4; ++e) {
      const unsigned u = __float_as_uint(fv[e]);
      const ushort hi = (ushort)((u + 0x7fffu + ((u>>16)&1u)) >> 16);
      const float res = fv[e] - __uint_as_float((unsigned)hi << 16);
      const unsigned u2 = __float_as_uint(res);
      hh[e] = hi;
      ll[e] = (ushort)((u2 + 0x7fffu + ((u2>>16)&1u)) >> 16);
    }
    const ushort4 h = make_ushort4(hh[0],hh[1],hh[2],hh[3]);
    const ushort4 lo = make_ushort4(ll[0],ll[1],ll[2],ll[3]);
    if (i < NA) { ((ushort4*)aHi)[i] = h;    ((ushort4*)aLo)[i] = lo; }
    else        { ((ushort4*)bHi)[i-NA] = h; ((ushort4*)bLo)[i-NA] = lo; }
  }
}

// ---------------- Kernel 1: Gram matrices + norms (fp32, LDS D-tiled) ----------------
__global__ __launch_bounds__(256) void gram_kernel(
    const float* __restrict__ imgs, const float* __restrict__ caps,
    float* __restrict__ gI, float* __restrict__ nI,
    float* __restrict__ gC, float* __restrict__ nC)
{
  __shared__ __align__(16) float L[LN*132];   // max 48 rows x 132
  const int b = blockIdx.x, tid = threadIdx.x;
  if (b < INN) {
    const float* base = imgs + (size_t)b*RN*DN;
    const int rg = tid/12, cg = tid - (tid/12)*12;   // 18x12 teams, 216 active
    const bool active = tid < 216;
    float a[2][3];
    #pragma unroll
    for (int u = 0; u < 2; ++u)
      #pragma unroll
      for (int v = 0; v < 3; ++v) a[u][v] = 0.f;
    for (int d0 = 0; d0 < DN; d0 += 128) {
      __syncthreads();
      for (int idx = tid; idx < RN*32; idx += 256) {
        const int row = idx >> 5, ch = idx & 31;
        *(float4*)&L[row*132 + ch*4] = *(const float4*)(base + row*DN + d0 + ch*4);
      }
      __syncthreads();
      if (active) {
        const float* r0 = &L[(2*rg)*132],   * r1 = &L[(2*rg+1)*132];
        const float* c0 = &L[(3*cg)*132],   * c1 = &L[(3*cg+1)*132], * c2 = &L[(3*cg+2)*132];
        #pragma unroll
        for (int k = 0; k < 32; ++k) {
          const float4 x0 = *(const float4*)(r0 + k*4);
          const float4 x1 = *(const float4*)(r1 + k*4);
          const float4 y0 = *(const float4*)(c0 + k*4);
          const float4 y1 = *(const float4*)(c1 + k*4);
          const float4 y2 = *(const float4*)(c2 + k*4);
          a[0][0] += dot4(x0,y0); a[0][1] += dot4(x0,y1); a[0][2] += dot4(x0,y2);
          a[1][0] += dot4(x1,y0); a[1][1] += dot4(x1,y1); a[1][2] += dot4(x1,y2);
        }
      }
    }
    if (active) {
      float* gb = gI + (size_t)b*RN*RN;
      #pragma unroll
      for (int u = 0; u < 2; ++u)
        #pragma unroll
        for (int v = 0; v < 3; ++v) {
          const int r = 2*rg + u, s = 3*cg + v;
          gb[r*RN + s] = a[u][v];
          if (r == s) nI[b*RN + r] = sqrtf(fmaxf(a[u][v], 1e-16f));
        }
    }
  } else {
    const int c = b - INN;
    const float* base = caps + (size_t)c*LN*DN;
    const int rg = tid >> 4, cg = tid & 15;          // 16x16 teams, all 256 active
    float a[3][3];
    #pragma unroll
    for (int u = 0; u < 3; ++u)
      #pragma unroll
      for (int v = 0; v < 3; ++v) a[u][v] = 0.f;
    for (int d0 = 0; d0 < DN; d0 += 128) {
      __syncthreads();
      for (int idx = tid; idx < LN*32; idx += 256) {
        const int row = idx >> 5, ch = idx & 31;
        *(float4*)&L[row*132 + ch*4] = *(const float4*)(base + row*DN + d0 + ch*4);
      }
      __syncthreads();
      const float* r0 = &L[(3*rg)*132],   * r1 = &L[(3*rg+1)*132], * r2 = &L[(3*rg+2)*132];
      const float* c0 = &L[(3*cg)*132],   * c1 = &L[(3*cg+1)*132], * c2 = &L[(3*cg+2)*132];
      #pragma unroll
      for (int k = 0; k < 32; ++k) {
        const float4 x0 = *(const float4*)(r0 + k*4);
        const float4 x1 = *(const float4*)(r1 + k*4);
        const float4 x2 = *(const float4*)(r2 + k*4);
        const float4 y0 = *(const float4*)(c0 + k*4);
        const float4 y1 = *(const float4*)(c1 + k*4);
        const float4 y2 = *(const float4*)(c2 + k*4);
        a[0][0] += dot4(x0,y0); a[0][1] += dot4(x0,y1); a[0][2] += dot4(x0,y2);
        a[1][0] += dot4(x1,y0); a[1][1] += dot4(x1,y1); a[1][2] += dot4(x1,y2);
        a[2][0] += dot4(x2,y0); a[2][1] += dot4(x2,y1); a[2][2] += dot4(x2,y2);
      }
    }
    float* gb = gC + (size_t)c*LN*LN;
    #pragma unroll
    for (int u = 0; u < 3; ++u)
      #pragma unroll
      for (int v = 0; v < 3; ++v) {
        const int r = 3*rg + u, s = 3*cg + v;
        gb[r*LN + s] = a[u][v];
        if (r == s) nC[c*LN + r] = sqrtf(fmaxf(a[u][v], 1e-16f));
      }
  }
}

// ---------------- Kernel 2: dots GEMM via bf16x3 MFMA ----------------
__global__ __launch_bounds__(256) void dots_gemm_mfma(
    const ushort* __restrict__ aHi, const ushort* __restrict__ aLo,
    const ushort* __restrict__ bHi, const ushort* __restrict__ bLo,
    float* __restrict__ dots, int arow0)
{
  __shared__ __align__(16) ushort sT[16384];   // Ah Al Bh Bl, 8KB each
  const int tid = threadIdx.x;
  const int wv = tid >> 6, lane = tid & 63;
  const int l15 = lane & 15, kg = lane >> 4;
  const int wr = wv >> 1, wc = wv & 1;
  const int M0 = blockIdx.y * 128;
  const int N0 = blockIdx.x * 128;

  int offA[4], offB[4];
  #pragma unroll
  for (int f = 0; f < 4; ++f) {
    const int rA = wr*64 + f*16 + l15;
    offA[f] = rA*32 + ((kg ^ ((rA>>1)&3)) << 3);
    const int rB = wc*64 + f*16 + l15;
    offB[f] = rB*32 + ((kg ^ ((rB>>1)&3)) << 3);
  }
  int srow[2], sgk[2]; unsigned dOff[2];
  #pragma unroll
  for (int h = 0; h < 2; ++h) {
    const int ch = h*256 + wv*64 + lane;
    const int row = ch >> 2, gp = ch & 3;
    srow[h] = row;
    sgk[h] = (gp ^ ((row>>1)&3)) * 8;
    dOff[h] = (unsigned)(h*256 + wv*64) * 8;
  }

  f32x4 acc[4][4];
  #pragma unroll
  for (int mf = 0; mf < 4; ++mf)
    #pragma unroll
    for (int nf = 0; nf < 4; ++nf) acc[mf][nf] = (f32x4){0.f,0.f,0.f,0.f};

  const size_t aR = (size_t)(arow0 + M0);
  for (int k0 = 0; k0 < DN; k0 += 32) {
    __syncthreads();
    #pragma unroll
    for (int h = 0; h < 2; ++h) {
      const size_t ao = (aR + srow[h])*DN + k0 + sgk[h];
      const size_t bo = ((size_t)(N0 + srow[h]))*DN + k0 + sgk[h];
      gload16u(aHi + ao, sT + dOff[h]);
      gload16u(aLo + ao, sT + 4096 + dOff[h]);
      gload16u(bHi + bo, sT + 8192 + dOff[h]);
      gload16u(bLo + bo, sT + 12288 + dOff[h]);
    }
    asm volatile("s_waitcnt vmcnt(0)" ::: "memory");
    __syncthreads();
    s16x8 ah[4], al[4], bh[4], bl[4];
    #pragma unroll
    for (int f = 0; f < 4; ++f) {
      ah[f] = *(const s16x8*)&sT[offA[f]];
      al[f] = *(const s16x8*)&sT[4096 + offA[f]];
      bh[f] = *(const s16x8*)&sT[8192 + offB[f]];
      bl[f] = *(const s16x8*)&sT[12288 + offB[f]];
    }
    #pragma unroll
    for (int mf = 0; mf < 4; ++mf)
      #pragma unroll
      for (int nf = 0; nf < 4; ++nf) {
        acc[mf][nf] = __builtin_amdgcn_mfma_f32_16x16x32_bf16(ah[mf], bh[nf], acc[mf][nf], 0,0,0);
        acc[mf][nf] = __builtin_amdgcn_mfma_f32_16x16x32_bf16(ah[mf], bl[nf], acc[mf][nf], 0,0,0);
        acc[mf][nf] = __builtin_amdgcn_mfma_f32_16x16x32_bf16(al[mf], bh[nf], acc[mf][nf], 0,0,0);
      }
  }
  #pragma unroll
  for (int mf = 0; mf < 4; ++mf)
    #pragma unroll
    for (int nf = 0; nf < 4; ++nf) {
      const int n = N0 + wc*64 + nf*16 + l15;
      #pragma unroll
      for (int r = 0; r < 4; ++r) {
        const int m = M0 + wr*64 + mf*16 + kg*4 + r;
        dots[(size_t)m*NT + n] = acc[mf][nf][r];
      }
    }
}

// ---------------- Kernel 3: attention + scores ----------------
// R10: TIA=2 (42.9KB LDS -> 3 blocks/CU, occupancy 25%->37.5%) with a UNIFIED
// virtual-row loop (96 t2i + 72 i2t rows over 3x64 team-passes, 87.5% slot
// efficiency — same issued work as TIA=4). Type boundary at vrow 96 is
// 16-team (wave) aligned: no intra-wave divergence.
// R8 lesson stands: one row per team, ~12 live floats; do NOT re-batch rows.
__global__ __launch_bounds__(256) void attn_kernel(
    const float* __restrict__ dots, const int* __restrict__ cap_lens,
    const float* __restrict__ gI, const float* __restrict__ nI,
    const float* __restrict__ gC, const float* __restrict__ nC,
    float* __restrict__ scores, int cbase)
{
  __shared__ float sDots[LN][RTA+1];                // 48 x 73, 14.0KB
  __shared__ __align__(16) float sGi4[TIA*RN*48];   // [2][36][48], 13.8KB
  __shared__ __align__(16) float sGc[LN*48];        // 9.2KB
  __shared__ float sColInv[TIA*RN];   // 72
  __shared__ float sRowInv[TIA*LN];   // 96
  __shared__ float sCapN[LN];
  __shared__ float sImgN[TIA*RN];
  __shared__ float sEt[TIA*LN];       // 96
  __shared__ float sEi[TIA*RN];       // 72

  const int cl = blockIdx.y;
  const int c  = cbase + cl;
  const int it = blockIdx.x;          // 0..63
  const int tid = threadIdx.x;
  const int nw = cap_lens[c];
  const float nwf = (float)nw;

  for (int idx = tid; idx < LN*RTA/4; idx += 256) {
    const int l = idx / (RTA/4), jseg = idx - l*(RTA/4);
    const float4 v = *(const float4*)(dots + ((size_t)cl*LN + l)*NT + (size_t)it*RTA + jseg*4);
    float* dst = &sDots[l][jseg*4];
    dst[0]=v.x; dst[1]=v.y; dst[2]=v.z; dst[3]=v.w;
  }
  for (int idx = tid; idx < TIA*RN*48/4; idx += 256)
    ((float4*)sGi4)[idx] = make_float4(0.f,0.f,0.f,0.f);
  for (int idx = tid; idx < 576; idx += 256) {
    const int rw = idx/12, mq = idx - rw*12;
    *(float4*)&sGc[rw*48 + mq*4] = *(const float4*)(gC + (size_t)c*LN*LN + rw*LN + mq*4);
  }
  if (tid < LN) sCapN[tid] = nC[c*LN + tid];
  if (tid < TIA*RN) sImgN[tid] = nI[it*TIA*RN + tid];
  __syncthreads();

  for (int idx = tid; idx < TIA*RN*RN; idx += 256) {
    const int i = idx / (RN*RN), rem = idx - i*(RN*RN);
    const int s = rem / RN, col = rem - s*RN;
    const int blk = col / 9, cib = col - blk*9;
    sGi4[(i*RN + s)*48 + blk*12 + cib] = gI[(size_t)(it*TIA+i)*RN*RN + rem];
  }
  if (tid < TIA*RN) {
    const int i = tid/RN, r = tid - i*RN;
    float s = 0.f;
    for (int l = 0; l < LN; ++l) { const float v = leaky(sDots[l][i*RN+r]); s += v*v; }
    sColInv[tid] = __builtin_amdgcn_rcpf(sqrtf(s) + EPSF);
  }
  if (tid < TIA*LN) {
    const int i = tid/LN, l = tid - i*LN;
    float s = 0.f;
    for (int r = 0; r < RN; ++r) { const float v = leaky(sDots[l][i*RN+r]); s += v*v; }
    sRowInv[tid] = __builtin_amdgcn_rcpf(sqrtf(s) + EPSF);
  }
  __syncthreads();

  const int team = tid >> 2, q4 = tid & 3;

  // ===== unified row loop: vrow 0..95 = t2i (i*48+l), 96..167 = i2t (i*36+r) =====
  #pragma unroll 1
  for (int pass = 0; pass < 3; ++pass) {
    const int vrow = pass*64 + team;
    if (vrow < TIA*LN) {
      // ---- t2i ----
      const int i = vrow / LN, l = vrow - i*LN;
      const int cb = i*RN + q4*9;
      float d9[9], x12[12];
      #pragma unroll
      for (int j = 0; j < 9; ++j) d9[j] = sDots[l][cb + j];
      float m = -1e30f;
      #pragma unroll
      for (int j = 0; j < 9; ++j) {
        const float v = leaky(d9[j]) * sColInv[cb + j] * LSM;
        x12[j] = v; m = fmaxf(m, v);
      }
      m = fmaxf(m, __shfl_xor(m, 1, 4));
      m = fmaxf(m, __shfl_xor(m, 2, 4));
      float se = 0.f;
      #pragma unroll
      for (int j = 0; j < 9; ++j) { const float e = __expf(x12[j] - m); x12[j] = e; se += e; }
      x12[9] = x12[10] = x12[11] = 0.f;
      se += __shfl_xor(se, 1, 4); se += __shfl_xor(se, 2, 4);
      const float inv = __builtin_amdgcn_rcpf(se);
      float s = 0.f;
      #pragma unroll
      for (int j = 0; j < 9; ++j) { const float p = x12[j]*inv; x12[j] = p; s += p; }
      s += __shfl_xor(s, 1, 4); s += __shfl_xor(s, 2, 4);
      float ts = 0.f;
      #pragma unroll
      for (int j = 0; j < 9; ++j) {
        const float tv = (x12[j]*36.f - s > 0.f) ? x12[j] : 0.f;
        x12[j] = tv; ts += tv;
      }
      ts += __shfl_xor(ts, 1, 4); ts += __shfl_xor(ts, 2, 4);
      const float den = (ts > 0.f) ? ts : 1.f;
      const float invd = __builtin_amdgcn_rcpf(den);
      float w12 = 0.f;
      #pragma unroll
      for (int j = 0; j < 9; ++j) w12 += x12[j]*d9[j];
      w12 += __shfl_xor(w12, 1, 4); w12 += __shfl_xor(w12, 2, 4);
      float qq = 0.f;
      const float* giB = sGi4 + (size_t)i*RN*48 + q4*12;
      #pragma unroll
      for (int sl = 0; sl < 4; ++sl) {
        #pragma unroll
        for (int si = 0; si < 9; ++si) {
          const float tv = __shfl(x12[si], sl, 4);
          const float4* gr = (const float4*)(giB + (sl*9 + si)*48);
          const float4 g0 = gr[0], g1 = gr[1], g2 = gr[2];
          const float p =
            x12[0]*g0.x + x12[1]*g0.y + x12[2]*g0.z + x12[3]*g0.w +
            x12[4]*g1.x + x12[5]*g1.y + x12[6]*g1.z + x12[7]*g1.w +
            x12[8]*g2.x + x12[9]*g2.y + x12[10]*g2.z + x12[11]*g2.w;
          qq += tv * p;
        }
      }
      qq += __shfl_xor(qq, 1, 4); qq += __shfl_xor(qq, 2, 4);
      if (q4 == 0) {
        const float w2 = sqrtf(fmaxf(qq*invd*invd, 1e-16f));
        const float sim = (w12*invd) * __builtin_amdgcn_rcpf(fmaxf(sCapN[l]*w2, EPSF));
        sEt[vrow] = (l < nw) ? __expf(LLSE*sim) : 0.f;
      }
    } else {
      // ---- i2t ----
      const int rowid = vrow - TIA*LN;
      if (rowid < TIA*RN) {
        const int i = rowid / RN, r = rowid - i*RN;
        float d12[12], x12[12];
        #pragma unroll
        for (int j = 0; j < 12; ++j) d12[j] = sDots[q4*12+j][i*RN + r];
        float m = -1e30f;
        #pragma unroll
        for (int j = 0; j < 12; ++j) {
          const int l = q4*12 + j;
          const float v = (l < nw) ? leaky(d12[j]) * sRowInv[i*LN + l] * LSM : -1e9f;
          x12[j] = v; m = fmaxf(m, v);
        }
        m = fmaxf(m, __shfl_xor(m, 1, 4));
        m = fmaxf(m, __shfl_xor(m, 2, 4));
        float se = 0.f;
        #pragma unroll
        for (int j = 0; j < 12; ++j) { const float e = __expf(x12[j] - m); x12[j] = e; se += e; }
        se += __shfl_xor(se, 1, 4); se += __shfl_xor(se, 2, 4);
        const float inv = __builtin_amdgcn_rcpf(se);
        float s = 0.f;
        #pragma unroll
        for (int j = 0; j < 12; ++j) { const float p = x12[j]*inv; x12[j] = p; s += p; }
        s += __shfl_xor(s, 1, 4); s += __shfl_xor(s, 2, 4);
        float ts = 0.f;
        #pragma unroll
        for (int j = 0; j < 12; ++j) {
          const float tv = (x12[j]*nwf - s > 0.f) ? x12[j] : 0.f;
          x12[j] = tv; ts += tv;
        }
        ts += __shfl_xor(ts, 1, 4); ts += __shfl_xor(ts, 2, 4);
        const float den = (ts > 0.f) ? ts : 1.f;
        const float invd = __builtin_amdgcn_rcpf(den);
        float w12 = 0.f;
        #pragma unroll
        for (int j = 0; j < 12; ++j) w12 += x12[j]*d12[j];
        w12 += __shfl_xor(w12, 1, 4); w12 += __shfl_xor(w12, 2, 4);
        float qq = 0.f;
        const float* gcB = sGc + q4*12;
        #pragma unroll
        for (int sl = 0; sl < 4; ++sl) {
          #pragma unroll
          for (int si = 0; si < 12; ++si) {
            const float tv = __shfl(x12[si], sl, 4);
            const float4* gr = (const float4*)(gcB + (sl*12 + si)*48);
            const float4 g0 = gr[0], g1 = gr[1], g2 = gr[2];
            const float p =
              x12[0]*g0.x + x12[1]*g0.y + x12[2]*g0.z + x12[3]*g0.w +
              x12[4]*g1.x + x12[5]*g1.y + x12[6]*g1.z + x12[7]*g1.w +
              x12[8]*g2.x + x12[9]*g2.y + x12[10]*g2.z + x12[11]*g2.w;
            qq += tv * p;
          }
        }
        qq += __shfl_xor(qq, 1, 4); qq += __shfl_xor(qq, 2, 4);
        if (q4 == 0) {
          const float w2 = sqrtf(fmaxf(qq*invd*invd, 1e-16f));
          const float sim = (w12*invd) * __builtin_amdgcn_rcpf(fmaxf(sImgN[rowid]*w2, EPSF));
          sEi[rowid] = __expf(LLSE*sim);
        }
      }
    }
  }
  __syncthreads();
  if (tid < TIA) {
    float st = 0.f, si2 = 0.f;
    for (int l = 0; l < LN; ++l) st += sEt[tid*LN + l];
    for (int r = 0; r < RN; ++r) si2 += sEi[tid*RN + r];
    scores[(size_t)(it*TIA + tid)*CN + c] = __logf(st)/LLSE + __logf(si2)/LLSE;
  }
}

// ---------------- Kernel 4: margin ranking loss ----------------
__global__ __launch_bounds__(128) void loss_kernel(
    const float* __restrict__ S, float* __restrict__ out)
{
  __shared__ float red[128];
  const int t = threadIdx.x;
  const float d = S[t*CN + t];
  float m1 = -1e30f, m2 = -1e30f;
  for (int cc = 0; cc < CN; ++cc)
    if (cc != t) m1 = fmaxf(m1, 0.2f + S[t*CN+cc] - d);
  for (int i2 = 0; i2 < INN; ++i2)
    if (i2 != t) m2 = fmaxf(m2, 0.2f + S[i2*CN+t] - d);
  red[t] = fmaxf(m1, 0.f) + fmaxf(m2, 0.f);
  __syncthreads();
  for (int s = 64; s > 0; s >>= 1) {
    if (t < s) red[t] += red[t+s];
    __syncthreads();
  }
  if (t == 0) out[0] = red[0];
}

extern "C" void kernel_launch(void* const* d_in, const int* in_sizes, int n_in,
                              void* d_out, int out_size, void* d_ws, size_t ws_size,
                              hipStream_t stream) {
  (void)in_sizes; (void)n_in; (void)out_size;
  const float* imgs = (const float*)d_in[0];
  const float* caps = (const float*)d_in[1];
  const int*   lens = (const int*)d_in[2];

  const size_t bfUS = 2*((size_t)MT + NT)*DN;
  const size_t smallF = (size_t)INN*RN*RN + INN*RN + (size_t)CN*LN*LN + CN*LN + (size_t)INN*CN;
  int g = CN;
  while (g > 8) {
    const size_t need = bfUS*2 + (smallF + (size_t)g*LN*NT)*4;
    if (need <= ws_size) break;
    g >>= 1;
  }

  ushort* aHi = (ushort*)d_ws;
  ushort* aLo = aHi + (size_t)MT*DN;
  ushort* bHi = aLo + (size_t)MT*DN;
  ushort* bLo = bHi + (size_t)NT*DN;
  float* fbase = (float*)(bLo + (size_t)NT*DN);
  float* gI     = fbase;
  float* nI     = gI + (size_t)INN*RN*RN;
  float* gC     = nI + (size_t)INN*RN;
  float* nC     = gC + (size_t)CN*LN*LN;
  float* scores = nC + (size_t)CN*LN;
  float* dots   = scores + (size_t)INN*CN;

  conv_kernel<<<dim3(1024), dim3(256), 0, stream>>>(caps, imgs, aHi, aLo, bHi, bLo);
  gram_kernel<<<dim3(INN+CN), dim3(256), 0, stream>>>(imgs, caps, gI, nI, gC, nC);
  for (int c0 = 0; c0 < CN; c0 += g) {
    dots_gemm_mfma<<<dim3(NT/128, g*LN/128), dim3(256), 0, stream>>>(
        aHi, aLo, bHi, bLo, dots, c0*LN);
    attn_kernel<<<dim3(INN/TIA, g), dim3(256), 0, stream>>>(
        dots, lens, gI, nI, gC, nC, scores, c0);
  }
  loss_kernel<<<dim3(1), dim3(128), 0, stream>>>(scores, (float*)d_out);
}

// Round 11
// 447.010 us; speedup vs baseline: 3.0676x; 1.0289x over previous
//
#include <hip/hip_runtime.h>
#include <math.h>

#define CN 128   // captions
#define INN 128  // images
#define LN 48    // words
#define RN 36    // regions
#define DN 1024  // feature dim
#define TIA 2    // images per attn block
#define RTA (TIA*RN)   // 72
#define MT 6144  // CN*LN
#define NT 4608  // INN*RN
#define EPSF 1e-8f
#define LSM 9.0f
#define LLSE 6.0f

__device__ __forceinline__ float leaky(float x){ return x > 0.f ? x : 0.1f*x; }
__device__ __forceinline__ float dot4(float4 a, float4 b){
  return a.x*b.x + a.y*b.y + a.z*b.z + a.w*b.w;
}

typedef const __attribute__((address_space(1))) unsigned int* gp_t;
typedef __attribute__((address_space(3))) unsigned int* lp_t;
__device__ __forceinline__ void gload16u(const ushort* g, ushort* l) {
  __builtin_amdgcn_global_load_lds((gp_t)g, (lp_t)l, 16, 0, 0);
}

typedef short s16x8 __attribute__((ext_vector_type(8)));
typedef float f32x4 __attribute__((ext_vector_type(4)));

// ---------------- Kernel 0: fp32 -> bf16 hi/lo split (RNE) ----------------
__global__ __launch_bounds__(256) void conv_kernel(
    const float* __restrict__ caps, const float* __restrict__ imgs,
    ushort* __restrict__ aHi, ushort* __restrict__ aLo,
    ushort* __restrict__ bHi, ushort* __restrict__ bLo)
{
  const int NA = MT*DN/4, NB = NT*DN/4;
  for (int i = blockIdx.x*256 + threadIdx.x; i < NA + NB; i += gridDim.x*256) {
    const float4 v = (i < NA) ? ((const float4*)caps)[i] : ((const float4*)imgs)[i - NA];
    const float fv[4] = {v.x, v.y, v.z, v.w};
    ushort hh[4], ll[4];
    #pragma unroll
    for (int e = 0; e < 4; ++e) {
      const unsigned u = __float_as_uint(fv[e]);
      const ushort hi = (ushort)((u + 0x7fffu + ((u>>16)&1u)) >> 16);
      const float res = fv[e] - __uint_as_float((unsigned)hi << 16);
      const unsigned u2 = __float_as_uint(res);
      hh[e] = hi;
      ll[e] = (ushort)((u2 + 0x7fffu + ((u2>>16)&1u)) >> 16);
    }
    const ushort4 h = make_ushort4(hh[0],hh[1],hh[2],hh[3]);
    const ushort4 lo = make_ushort4(ll[0],ll[1],ll[2],ll[3]);
    if (i < NA) { ((ushort4*)aHi)[i] = h;    ((ushort4*)aLo)[i] = lo; }
    else        { ((ushort4*)bHi)[i-NA] = h; ((ushort4*)bLo)[i-NA] = lo; }
  }
}

// ---------------- Kernel 1: Gram matrices + norms (fp32, LDS D-tiled) ----------------
__global__ __launch_bounds__(256) void gram_kernel(
    const float* __restrict__ imgs, const float* __restrict__ caps,
    float* __restrict__ gI, float* __restrict__ nI,
    float* __restrict__ gC, float* __restrict__ nC)
{
  __shared__ __align__(16) float L[LN*132];   // max 48 rows x 132
  const int b = blockIdx.x, tid = threadIdx.x;
  if (b < INN) {
    const float* base = imgs + (size_t)b*RN*DN;
    const int rg = tid/12, cg = tid - (tid/12)*12;   // 18x12 teams, 216 active
    const bool active = tid < 216;
    float a[2][3];
    #pragma unroll
    for (int u = 0; u < 2; ++u)
      #pragma unroll
      for (int v = 0; v < 3; ++v) a[u][v] = 0.f;
    for (int d0 = 0; d0 < DN; d0 += 128) {
      __syncthreads();
      for (int idx = tid; idx < RN*32; idx += 256) {
        const int row = idx >> 5, ch = idx & 31;
        *(float4*)&L[row*132 + ch*4] = *(const float4*)(base + row*DN + d0 + ch*4);
      }
      __syncthreads();
      if (active) {
        const float* r0 = &L[(2*rg)*132],   * r1 = &L[(2*rg+1)*132];
        const float* c0 = &L[(3*cg)*132],   * c1 = &L[(3*cg+1)*132], * c2 = &L[(3*cg+2)*132];
        #pragma unroll
        for (int k = 0; k < 32; ++k) {
          const float4 x0 = *(const float4*)(r0 + k*4);
          const float4 x1 = *(const float4*)(r1 + k*4);
          const float4 y0 = *(const float4*)(c0 + k*4);
          const float4 y1 = *(const float4*)(c1 + k*4);
          const float4 y2 = *(const float4*)(c2 + k*4);
          a[0][0] += dot4(x0,y0); a[0][1] += dot4(x0,y1); a[0][2] += dot4(x0,y2);
          a[1][0] += dot4(x1,y0); a[1][1] += dot4(x1,y1); a[1][2] += dot4(x1,y2);
        }
      }
    }
    if (active) {
      float* gb = gI + (size_t)b*RN*RN;
      #pragma unroll
      for (int u = 0; u < 2; ++u)
        #pragma unroll
        for (int v = 0; v < 3; ++v) {
          const int r = 2*rg + u, s = 3*cg + v;
          gb[r*RN + s] = a[u][v];
          if (r == s) nI[b*RN + r] = sqrtf(fmaxf(a[u][v], 1e-16f));
        }
    }
  } else {
    const int c = b - INN;
    const float* base = caps + (size_t)c*LN*DN;
    const int rg = tid >> 4, cg = tid & 15;          // 16x16 teams, all 256 active
    float a[3][3];
    #pragma unroll
    for (int u = 0; u < 3; ++u)
      #pragma unroll
      for (int v = 0; v < 3; ++v) a[u][v] = 0.f;
    for (int d0 = 0; d0 < DN; d0 += 128) {
      __syncthreads();
      for (int idx = tid; idx < LN*32; idx += 256) {
        const int row = idx >> 5, ch = idx & 31;
        *(float4*)&L[row*132 + ch*4] = *(const float4*)(base + row*DN + d0 + ch*4);
      }
      __syncthreads();
      const float* r0 = &L[(3*rg)*132],   * r1 = &L[(3*rg+1)*132], * r2 = &L[(3*rg+2)*132];
      const float* c0 = &L[(3*cg)*132],   * c1 = &L[(3*cg+1)*132], * c2 = &L[(3*cg+2)*132];
      #pragma unroll
      for (int k = 0; k < 32; ++k) {
        const float4 x0 = *(const float4*)(r0 + k*4);
        const float4 x1 = *(const float4*)(r1 + k*4);
        const float4 x2 = *(const float4*)(r2 + k*4);
        const float4 y0 = *(const float4*)(c0 + k*4);
        const float4 y1 = *(const float4*)(c1 + k*4);
        const float4 y2 = *(const float4*)(c2 + k*4);
        a[0][0] += dot4(x0,y0); a[0][1] += dot4(x0,y1); a[0][2] += dot4(x0,y2);
        a[1][0] += dot4(x1,y0); a[1][1] += dot4(x1,y1); a[1][2] += dot4(x1,y2);
        a[2][0] += dot4(x2,y0); a[2][1] += dot4(x2,y1); a[2][2] += dot4(x2,y2);
      }
    }
    float* gb = gC + (size_t)c*LN*LN;
    #pragma unroll
    for (int u = 0; u < 3; ++u)
      #pragma unroll
      for (int v = 0; v < 3; ++v) {
        const int r = 3*rg + u, s = 3*cg + v;
        gb[r*LN + s] = a[u][v];
        if (r == s) nC[c*LN + r] = sqrtf(fmaxf(a[u][v], 1e-16f));
      }
  }
}

// ---------------- Kernel 2: dots GEMM via bf16x3 MFMA ----------------
__global__ __launch_bounds__(256) void dots_gemm_mfma(
    const ushort* __restrict__ aHi, const ushort* __restrict__ aLo,
    const ushort* __restrict__ bHi, const ushort* __restrict__ bLo,
    float* __restrict__ dots, int arow0)
{
  __shared__ __align__(16) ushort sT[16384];   // Ah Al Bh Bl, 8KB each
  const int tid = threadIdx.x;
  const int wv = tid >> 6, lane = tid & 63;
  const int l15 = lane & 15, kg = lane >> 4;
  const int wr = wv >> 1, wc = wv & 1;
  const int M0 = blockIdx.y * 128;
  const int N0 = blockIdx.x * 128;

  int offA[4], offB[4];
  #pragma unroll
  for (int f = 0; f < 4; ++f) {
    const int rA = wr*64 + f*16 + l15;
    offA[f] = rA*32 + ((kg ^ ((rA>>1)&3)) << 3);
    const int rB = wc*64 + f*16 + l15;
    offB[f] = rB*32 + ((kg ^ ((rB>>1)&3)) << 3);
  }
  int srow[2], sgk[2]; unsigned dOff[2];
  #pragma unroll
  for (int h = 0; h < 2; ++h) {
    const int ch = h*256 + wv*64 + lane;
    const int row = ch >> 2, gp = ch & 3;
    srow[h] = row;
    sgk[h] = (gp ^ ((row>>1)&3)) * 8;
    dOff[h] = (unsigned)(h*256 + wv*64) * 8;
  }

  f32x4 acc[4][4];
  #pragma unroll
  for (int mf = 0; mf < 4; ++mf)
    #pragma unroll
    for (int nf = 0; nf < 4; ++nf) acc[mf][nf] = (f32x4){0.f,0.f,0.f,0.f};

  const size_t aR = (size_t)(arow0 + M0);
  for (int k0 = 0; k0 < DN; k0 += 32) {
    __syncthreads();
    #pragma unroll
    for (int h = 0; h < 2; ++h) {
      const size_t ao = (aR + srow[h])*DN + k0 + sgk[h];
      const size_t bo = ((size_t)(N0 + srow[h]))*DN + k0 + sgk[h];
      gload16u(aHi + ao, sT + dOff[h]);
      gload16u(aLo + ao, sT + 4096 + dOff[h]);
      gload16u(bHi + bo, sT + 8192 + dOff[h]);
      gload16u(bLo + bo, sT + 12288 + dOff[h]);
    }
    asm volatile("s_waitcnt vmcnt(0)" ::: "memory");
    __syncthreads();
    s16x8 ah[4], al[4], bh[4], bl[4];
    #pragma unroll
    for (int f = 0; f < 4; ++f) {
      ah[f] = *(const s16x8*)&sT[offA[f]];
      al[f] = *(const s16x8*)&sT[4096 + offA[f]];
      bh[f] = *(const s16x8*)&sT[8192 + offB[f]];
      bl[f] = *(const s16x8*)&sT[12288 + offB[f]];
    }
    #pragma unroll
    for (int mf = 0; mf < 4; ++mf)
      #pragma unroll
      for (int nf = 0; nf < 4; ++nf) {
        acc[mf][nf] = __builtin_amdgcn_mfma_f32_16x16x32_bf16(ah[mf], bh[nf], acc[mf][nf], 0,0,0);
        acc[mf][nf] = __builtin_amdgcn_mfma_f32_16x16x32_bf16(ah[mf], bl[nf], acc[mf][nf], 0,0,0);
        acc[mf][nf] = __builtin_amdgcn_mfma_f32_16x16x32_bf16(al[mf], bh[nf], acc[mf][nf], 0,0,0);
      }
  }
  #pragma unroll
  for (int mf = 0; mf < 4; ++mf)
    #pragma unroll
    for (int nf = 0; nf < 4; ++nf) {
      const int n = N0 + wc*64 + nf*16 + l15;
      #pragma unroll
      for (int r = 0; r < 4; ++r) {
        const int m = M0 + wr*64 + mf*16 + kg*4 + r;
        dots[(size_t)m*NT + n] = acc[mf][nf][r];
      }
    }
}

// ---------------- Kernel 3: attention + scores ----------------
// R11 algebraic cuts (all exact up to fp rounding at ~1e-7 boundaries):
//  (1) softmax sum s == 1 and se cancels in focal renorm: work directly with
//      unnormalized e; predicate e*L > se; re = me/ts with ts = sum(me).
//  (2) exp args bounded in [-9,9] (l2norm * lambda): no max-subtract needed.
//  (3) lambda folded into sColInv/sRowInv; t2i qq dot truncated to 9 real terms.
// Structure unchanged from R10 (one row per 4-lane team; R8: do NOT re-batch).
__global__ __launch_bounds__(256) void attn_kernel(
    const float* __restrict__ dots, const int* __restrict__ cap_lens,
    const float* __restrict__ gI, const float* __restrict__ nI,
    const float* __restrict__ gC, const float* __restrict__ nC,
    float* __restrict__ scores, int cbase)
{
  __shared__ float sDots[LN][RTA+1];                // 48 x 73
  __shared__ __align__(16) float sGi4[TIA*RN*48];   // [2][36][48], blocks of 12 (9 valid + 3 pad)
  __shared__ __align__(16) float sGc[LN*48];        // [48][48]
  __shared__ float sColInv[TIA*RN];
  __shared__ float sRowInv[TIA*LN];
  __shared__ float sCapN[LN];
  __shared__ float sImgN[TIA*RN];
  __shared__ float sEt[TIA*LN];
  __shared__ float sEi[TIA*RN];

  const int cl = blockIdx.y;
  const int c  = cbase + cl;
  const int it = blockIdx.x;          // 0..63
  const int tid = threadIdx.x;
  const int nw = cap_lens[c];
  const float nwf = (float)nw;

  for (int idx = tid; idx < LN*RTA/4; idx += 256) {
    const int l = idx / (RTA/4), jseg = idx - l*(RTA/4);
    const float4 v = *(const float4*)(dots + ((size_t)cl*LN + l)*NT + (size_t)it*RTA + jseg*4);
    float* dst = &sDots[l][jseg*4];
    dst[0]=v.x; dst[1]=v.y; dst[2]=v.z; dst[3]=v.w;
  }
  for (int idx = tid; idx < TIA*RN*48/4; idx += 256)
    ((float4*)sGi4)[idx] = make_float4(0.f,0.f,0.f,0.f);
  for (int idx = tid; idx < 576; idx += 256) {
    const int rw = idx/12, mq = idx - rw*12;
    *(float4*)&sGc[rw*48 + mq*4] = *(const float4*)(gC + (size_t)c*LN*LN + rw*LN + mq*4);
  }
  if (tid < LN) sCapN[tid] = nC[c*LN + tid];
  if (tid < TIA*RN) sImgN[tid] = nI[it*TIA*RN + tid];
  __syncthreads();

  for (int idx = tid; idx < TIA*RN*RN; idx += 256) {
    const int i = idx / (RN*RN), rem = idx - i*(RN*RN);
    const int s = rem / RN, col = rem - s*RN;
    const int blk = col / 9, cib = col - blk*9;
    sGi4[(i*RN + s)*48 + blk*12 + cib] = gI[(size_t)(it*TIA+i)*RN*RN + rem];
  }
  if (tid < TIA*RN) {              // lambda folded in (cut 3)
    const int i = tid/RN, r = tid - i*RN;
    float s = 0.f;
    for (int l = 0; l < LN; ++l) { const float v = leaky(sDots[l][i*RN+r]); s += v*v; }
    sColInv[tid] = LSM * __builtin_amdgcn_rcpf(sqrtf(s) + EPSF);
  }
  if (tid < TIA*LN) {
    const int i = tid/LN, l = tid - i*LN;
    float s = 0.f;
    for (int r = 0; r < RN; ++r) { const float v = leaky(sDots[l][i*RN+r]); s += v*v; }
    sRowInv[tid] = LSM * __builtin_amdgcn_rcpf(sqrtf(s) + EPSF);
  }
  __syncthreads();

  const int team = tid >> 2, q4 = tid & 3;

  // ===== unified row loop: vrow 0..95 = t2i (i*48+l), 96..167 = i2t (i*36+r) =====
  #pragma unroll 1
  for (int pass = 0; pass < 3; ++pass) {
    const int vrow = pass*64 + team;
    if (vrow < TIA*LN) {
      // ---- t2i ----
      const int i = vrow / LN, l = vrow - i*LN;
      const int cb = i*RN + q4*9;
      float d9[9], x9[9];
      #pragma unroll
      for (int j = 0; j < 9; ++j) d9[j] = sDots[l][cb + j];
      float se = 0.f;
      #pragma unroll
      for (int j = 0; j < 9; ++j) {
        const float e = __expf(leaky(d9[j]) * sColInv[cb + j]);  // arg in [-9,9]
        x9[j] = e; se += e;
      }
      se += __shfl_xor(se, 1, 4); se += __shfl_xor(se, 2, 4);
      float ts = 0.f;
      #pragma unroll
      for (int j = 0; j < 9; ++j) {
        const float me = (x9[j]*36.f > se) ? x9[j] : 0.f;   // focal: p*36 > 1
        x9[j] = me; ts += me;
      }
      ts += __shfl_xor(ts, 1, 4); ts += __shfl_xor(ts, 2, 4);
      const float invd = __builtin_amdgcn_rcpf((ts > 0.f) ? ts : 1.f);
      float w12 = 0.f;
      #pragma unroll
      for (int j = 0; j < 9; ++j) w12 += x9[j]*d9[j];
      w12 += __shfl_xor(w12, 1, 4); w12 += __shfl_xor(w12, 2, 4);
      float qq = 0.f;
      const float* giB = sGi4 + (size_t)i*RN*48 + q4*12;
      #pragma unroll
      for (int sl = 0; sl < 4; ++sl) {
        #pragma unroll
        for (int si = 0; si < 9; ++si) {
          const float tv = __shfl(x9[si], sl, 4);
          const float4* gr = (const float4*)(giB + (sl*9 + si)*48);
          const float4 g0 = gr[0], g1 = gr[1];
          const float g8 = giB[(sl*9 + si)*48 + 8];
          const float p =
            x9[0]*g0.x + x9[1]*g0.y + x9[2]*g0.z + x9[3]*g0.w +
            x9[4]*g1.x + x9[5]*g1.y + x9[6]*g1.z + x9[7]*g1.w +
            x9[8]*g8;
          qq += tv * p;
        }
      }
      qq += __shfl_xor(qq, 1, 4); qq += __shfl_xor(qq, 2, 4);
      if (q4 == 0) {
        const float w2 = sqrtf(fmaxf(qq*invd*invd, 1e-16f));
        const float sim = (w12*invd) * __builtin_amdgcn_rcpf(fmaxf(sCapN[l]*w2, EPSF));
        sEt[vrow] = (l < nw) ? __expf(LLSE*sim) : 0.f;
      }
    } else {
      // ---- i2t ----
      const int rowid = vrow - TIA*LN;
      if (rowid < TIA*RN) {
        const int i = rowid / RN, r = rowid - i*RN;
        float d12[12], x12[12];
        #pragma unroll
        for (int j = 0; j < 12; ++j) d12[j] = sDots[q4*12+j][i*RN + r];
        float se = 0.f;
        #pragma unroll
        for (int j = 0; j < 12; ++j) {
          const int l = q4*12 + j;
          const float e = (l < nw) ? __expf(leaky(d12[j]) * sRowInv[i*LN + l]) : 0.f;
          x12[j] = e; se += e;
        }
        se += __shfl_xor(se, 1, 4); se += __shfl_xor(se, 2, 4);
        float ts = 0.f;
        #pragma unroll
        for (int j = 0; j < 12; ++j) {
          const float me = (x12[j]*nwf > se) ? x12[j] : 0.f;   // focal: p*nw > 1
          x12[j] = me; ts += me;
        }
        ts += __shfl_xor(ts, 1, 4); ts += __shfl_xor(ts, 2, 4);
        const float invd = __builtin_amdgcn_rcpf((ts > 0.f) ? ts : 1.f);
        float w12 = 0.f;
        #pragma unroll
        for (int j = 0; j < 12; ++j) w12 += x12[j]*d12[j];
        w12 += __shfl_xor(w12, 1, 4); w12 += __shfl_xor(w12, 2, 4);
        float qq = 0.f;
        const float* gcB = sGc + q4*12;
        #pragma unroll
        for (int sl = 0; sl < 4; ++sl) {
          #pragma unroll
          for (int si = 0; si < 12; ++si) {
            const float tv = __shfl(x12[si], sl, 4);
            const float4* gr = (const float4*)(gcB + (sl*12 + si)*48);
            const float4 g0 = gr[0], g1 = gr[1], g2 = gr[2];
            const float p =
              x12[0]*g0.x + x12[1]*g0.y + x12[2]*g0.z + x12[3]*g0.w +
              x12[4]*g1.x + x12[5]*g1.y + x12[6]*g1.z + x12[7]*g1.w +
              x12[8]*g2.x + x12[9]*g2.y + x12[10]*g2.z + x12[11]*g2.w;
            qq += tv * p;
          }
        }
        qq += __shfl_xor(qq, 1, 4); qq += __shfl_xor(qq, 2, 4);
        if (q4 == 0) {
          const float w2 = sqrtf(fmaxf(qq*invd*invd, 1e-16f));
          const float sim = (w12*invd) * __builtin_amdgcn_rcpf(fmaxf(sImgN[rowid]*w2, EPSF));
          sEi[rowid] = __expf(LLSE*sim);
        }
      }
    }
  }
  __syncthreads();
  if (tid < TIA) {
    float st = 0.f, si2 = 0.f;
    for (int l = 0; l < LN; ++l) st += sEt[tid*LN + l];
    for (int r = 0; r < RN; ++r) si2 += sEi[tid*RN + r];
    scores[(size_t)(it*TIA + tid)*CN + c] = __logf(st)/LLSE + __logf(si2)/LLSE;
  }
}

// ---------------- Kernel 4: margin ranking loss ----------------
__global__ __launch_bounds__(128) void loss_kernel(
    const float* __restrict__ S, float* __restrict__ out)
{
  __shared__ float red[128];
  const int t = threadIdx.x;
  const float d = S[t*CN + t];
  float m1 = -1e30f, m2 = -1e30f;
  for (int cc = 0; cc < CN; ++cc)
    if (cc != t) m1 = fmaxf(m1, 0.2f + S[t*CN+cc] - d);
  for (int i2 = 0; i2 < INN; ++i2)
    if (i2 != t) m2 = fmaxf(m2, 0.2f + S[i2*CN+t] - d);
  red[t] = fmaxf(m1, 0.f) + fmaxf(m2, 0.f);
  __syncthreads();
  for (int s = 64; s > 0; s >>= 1) {
    if (t < s) red[t] += red[t+s];
    __syncthreads();
  }
  if (t == 0) out[0] = red[0];
}

extern "C" void kernel_launch(void* const* d_in, const int* in_sizes, int n_in,
                              void* d_out, int out_size, void* d_ws, size_t ws_size,
                              hipStream_t stream) {
  (void)in_sizes; (void)n_in; (void)out_size;
  const float* imgs = (const float*)d_in[0];
  const float* caps = (const float*)d_in[1];
  const int*   lens = (const int*)d_in[2];

  const size_t bfUS = 2*((size_t)MT + NT)*DN;
  const size_t smallF = (size_t)INN*RN*RN + INN*RN + (size_t)CN*LN*LN + CN*LN + (size_t)INN*CN;
  int g = CN;
  while (g > 8) {
    const size_t need = bfUS*2 + (smallF + (size_t)g*LN*NT)*4;
    if (need <= ws_size) break;
    g >>= 1;
  }

  ushort* aHi = (ushort*)d_ws;
  ushort* aLo = aHi + (size_t)MT*DN;
  ushort* bHi = aLo + (size_t)MT*DN;
  ushort* bLo = bHi + (size_t)NT*DN;
  float* fbase = (float*)(bLo + (size_t)NT*DN);
  float* gI     = fbase;
  float* nI     = gI + (size_t)INN*RN*RN;
  float* gC     = nI + (size_t)INN*RN;
  float* nC     = gC + (size_t)CN*LN*LN;
  float* scores = nC + (size_t)CN*LN;
  float* dots   = scores + (size_t)INN*CN;

  conv_kernel<<<dim3(1024), dim3(256), 0, stream>>>(caps, imgs, aHi, aLo, bHi, bLo);
  gram_kernel<<<dim3(INN+CN), dim3(256), 0, stream>>>(imgs, caps, gI, nI, gC, nC);
  for (int c0 = 0; c0 < CN; c0 += g) {
    dots_gemm_mfma<<<dim3(NT/128, g*LN/128), dim3(256), 0, stream>>>(
        aHi, aLo, bHi, bLo, dots, c0*LN);
    attn_kernel<<<dim3(INN/TIA, g), dim3(256), 0, stream>>>(
        dots, lens, gI, nI, gC, nC, scores, c0);
  }
  loss_kernel<<<dim3(1), dim3(128), 0, stream>>>(scores, (float*)d_out);
}

// Round 12
// 440.118 us; speedup vs baseline: 3.1157x; 1.0157x over previous
//
#include <hip/hip_runtime.h>
#include <math.h>

#define CN 128   // captions
#define INN 128  // images
#define LN 48    // words
#define RN 36    // regions
#define DN 1024  // feature dim
#define TIA 2    // images per attn block
#define RTA (TIA*RN)   // 72
#define MT 6144  // CN*LN
#define NT 4608  // INN*RN
#define EPSF 1e-8f
#define LSM 9.0f
#define LLSE 6.0f

__device__ __forceinline__ float leaky(float x){ return x > 0.f ? x : 0.1f*x; }
__device__ __forceinline__ float dot4(float4 a, float4 b){
  return a.x*b.x + a.y*b.y + a.z*b.z + a.w*b.w;
}

typedef const __attribute__((address_space(1))) unsigned int* gp_t;
typedef __attribute__((address_space(3))) unsigned int* lp_t;
__device__ __forceinline__ void gload16u(const ushort* g, ushort* l) {
  __builtin_amdgcn_global_load_lds((gp_t)g, (lp_t)l, 16, 0, 0);
}

typedef short s16x8 __attribute__((ext_vector_type(8)));
typedef float f32x4 __attribute__((ext_vector_type(4)));

// RNE fp32 -> (hi, lo) bf16 pair
__device__ __forceinline__ void bf16split(float f, ushort& h, ushort& l) {
  const unsigned u = __float_as_uint(f);
  h = (ushort)((u + 0x7fffu + ((u>>16)&1u)) >> 16);
  const float res = f - __uint_as_float((unsigned)h << 16);
  const unsigned u2 = __float_as_uint(res);
  l = (ushort)((u2 + 0x7fffu + ((u2>>16)&1u)) >> 16);
}

// ---------------- Kernel 1: Gram matrices + norms + FUSED bf16 hi/lo emission ----------
// R12: former conv_kernel folded in — inputs are already staged in LDS here, so
// emit the bf16 planes from the staged tile (saves a full 45MB input re-read +
// one kernel launch). Emission is between the same barriers as compute.
__global__ __launch_bounds__(256) void gram_conv_kernel(
    const float* __restrict__ imgs, const float* __restrict__ caps,
    float* __restrict__ gI, float* __restrict__ nI,
    float* __restrict__ gC, float* __restrict__ nC,
    ushort* __restrict__ aHi, ushort* __restrict__ aLo,
    ushort* __restrict__ bHi, ushort* __restrict__ bLo)
{
  __shared__ __align__(16) float L[LN*132];   // max 48 rows x 132
  const int b = blockIdx.x, tid = threadIdx.x;
  if (b < INN) {
    const float* base = imgs + (size_t)b*RN*DN;
    const int rg = tid/12, cg = tid - (tid/12)*12;   // 18x12 teams, 216 active
    const bool active = tid < 216;
    float a[2][3];
    #pragma unroll
    for (int u = 0; u < 2; ++u)
      #pragma unroll
      for (int v = 0; v < 3; ++v) a[u][v] = 0.f;
    for (int d0 = 0; d0 < DN; d0 += 128) {
      __syncthreads();
      for (int idx = tid; idx < RN*32; idx += 256) {
        const int row = idx >> 5, ch = idx & 31;
        *(float4*)&L[row*132 + ch*4] = *(const float4*)(base + row*DN + d0 + ch*4);
      }
      __syncthreads();
      // fused bf16 emission from staged tile
      for (int idx = tid; idx < RN*32; idx += 256) {
        const int row = idx >> 5, ch = idx & 31;
        const float4 v = *(const float4*)&L[row*132 + ch*4];
        const float fv[4] = {v.x,v.y,v.z,v.w};
        ushort hh[4], ll[4];
        #pragma unroll
        for (int e = 0; e < 4; ++e) bf16split(fv[e], hh[e], ll[e]);
        const size_t off = (size_t)(b*RN + row)*DN + d0 + ch*4;
        *(ushort4*)(bHi + off) = make_ushort4(hh[0],hh[1],hh[2],hh[3]);
        *(ushort4*)(bLo + off) = make_ushort4(ll[0],ll[1],ll[2],ll[3]);
      }
      if (active) {
        const float* r0 = &L[(2*rg)*132],   * r1 = &L[(2*rg+1)*132];
        const float* c0 = &L[(3*cg)*132],   * c1 = &L[(3*cg+1)*132], * c2 = &L[(3*cg+2)*132];
        #pragma unroll
        for (int k = 0; k < 32; ++k) {
          const float4 x0 = *(const float4*)(r0 + k*4);
          const float4 x1 = *(const float4*)(r1 + k*4);
          const float4 y0 = *(const float4*)(c0 + k*4);
          const float4 y1 = *(const float4*)(c1 + k*4);
          const float4 y2 = *(const float4*)(c2 + k*4);
          a[0][0] += dot4(x0,y0); a[0][1] += dot4(x0,y1); a[0][2] += dot4(x0,y2);
          a[1][0] += dot4(x1,y0); a[1][1] += dot4(x1,y1); a[1][2] += dot4(x1,y2);
        }
      }
    }
    if (active) {
      float* gb = gI + (size_t)b*RN*RN;
      #pragma unroll
      for (int u = 0; u < 2; ++u)
        #pragma unroll
        for (int v = 0; v < 3; ++v) {
          const int r = 2*rg + u, s = 3*cg + v;
          gb[r*RN + s] = a[u][v];
          if (r == s) nI[b*RN + r] = sqrtf(fmaxf(a[u][v], 1e-16f));
        }
    }
  } else {
    const int c = b - INN;
    const float* base = caps + (size_t)c*LN*DN;
    const int rg = tid >> 4, cg = tid & 15;          // 16x16 teams, all 256 active
    float a[3][3];
    #pragma unroll
    for (int u = 0; u < 3; ++u)
      #pragma unroll
      for (int v = 0; v < 3; ++v) a[u][v] = 0.f;
    for (int d0 = 0; d0 < DN; d0 += 128) {
      __syncthreads();
      for (int idx = tid; idx < LN*32; idx += 256) {
        const int row = idx >> 5, ch = idx & 31;
        *(float4*)&L[row*132 + ch*4] = *(const float4*)(base + row*DN + d0 + ch*4);
      }
      __syncthreads();
      // fused bf16 emission from staged tile
      for (int idx = tid; idx < LN*32; idx += 256) {
        const int row = idx >> 5, ch = idx & 31;
        const float4 v = *(const float4*)&L[row*132 + ch*4];
        const float fv[4] = {v.x,v.y,v.z,v.w};
        ushort hh[4], ll[4];
        #pragma unroll
        for (int e = 0; e < 4; ++e) bf16split(fv[e], hh[e], ll[e]);
        const size_t off = (size_t)(c*LN + row)*DN + d0 + ch*4;
        *(ushort4*)(aHi + off) = make_ushort4(hh[0],hh[1],hh[2],hh[3]);
        *(ushort4*)(aLo + off) = make_ushort4(ll[0],ll[1],ll[2],ll[3]);
      }
      const float* r0 = &L[(3*rg)*132],   * r1 = &L[(3*rg+1)*132], * r2 = &L[(3*rg+2)*132];
      const float* c0 = &L[(3*cg)*132],   * c1 = &L[(3*cg+1)*132], * c2 = &L[(3*cg+2)*132];
      #pragma unroll
      for (int k = 0; k < 32; ++k) {
        const float4 x0 = *(const float4*)(r0 + k*4);
        const float4 x1 = *(const float4*)(r1 + k*4);
        const float4 x2 = *(const float4*)(r2 + k*4);
        const float4 y0 = *(const float4*)(c0 + k*4);
        const float4 y1 = *(const float4*)(c1 + k*4);
        const float4 y2 = *(const float4*)(c2 + k*4);
        a[0][0] += dot4(x0,y0); a[0][1] += dot4(x0,y1); a[0][2] += dot4(x0,y2);
        a[1][0] += dot4(x1,y0); a[1][1] += dot4(x1,y1); a[1][2] += dot4(x1,y2);
        a[2][0] += dot4(x2,y0); a[2][1] += dot4(x2,y1); a[2][2] += dot4(x2,y2);
      }
    }
    float* gb = gC + (size_t)c*LN*LN;
    #pragma unroll
    for (int u = 0; u < 3; ++u)
      #pragma unroll
      for (int v = 0; v < 3; ++v) {
        const int r = 3*rg + u, s = 3*cg + v;
        gb[r*LN + s] = a[u][v];
        if (r == s) nC[c*LN + r] = sqrtf(fmaxf(a[u][v], 1e-16f));
      }
  }
}

// ---------------- Kernel 2: dots GEMM via bf16x3 MFMA ----------------
__global__ __launch_bounds__(256) void dots_gemm_mfma(
    const ushort* __restrict__ aHi, const ushort* __restrict__ aLo,
    const ushort* __restrict__ bHi, const ushort* __restrict__ bLo,
    float* __restrict__ dots, int arow0)
{
  __shared__ __align__(16) ushort sT[16384];   // Ah Al Bh Bl, 8KB each
  const int tid = threadIdx.x;
  const int wv = tid >> 6, lane = tid & 63;
  const int l15 = lane & 15, kg = lane >> 4;
  const int wr = wv >> 1, wc = wv & 1;
  const int M0 = blockIdx.y * 128;
  const int N0 = blockIdx.x * 128;

  int offA[4], offB[4];
  #pragma unroll
  for (int f = 0; f < 4; ++f) {
    const int rA = wr*64 + f*16 + l15;
    offA[f] = rA*32 + ((kg ^ ((rA>>1)&3)) << 3);
    const int rB = wc*64 + f*16 + l15;
    offB[f] = rB*32 + ((kg ^ ((rB>>1)&3)) << 3);
  }
  int srow[2], sgk[2]; unsigned dOff[2];
  #pragma unroll
  for (int h = 0; h < 2; ++h) {
    const int ch = h*256 + wv*64 + lane;
    const int row = ch >> 2, gp = ch & 3;
    srow[h] = row;
    sgk[h] = (gp ^ ((row>>1)&3)) * 8;
    dOff[h] = (unsigned)(h*256 + wv*64) * 8;
  }

  f32x4 acc[4][4];
  #pragma unroll
  for (int mf = 0; mf < 4; ++mf)
    #pragma unroll
    for (int nf = 0; nf < 4; ++nf) acc[mf][nf] = (f32x4){0.f,0.f,0.f,0.f};

  const size_t aR = (size_t)(arow0 + M0);
  for (int k0 = 0; k0 < DN; k0 += 32) {
    __syncthreads();
    #pragma unroll
    for (int h = 0; h < 2; ++h) {
      const size_t ao = (aR + srow[h])*DN + k0 + sgk[h];
      const size_t bo = ((size_t)(N0 + srow[h]))*DN + k0 + sgk[h];
      gload16u(aHi + ao, sT + dOff[h]);
      gload16u(aLo + ao, sT + 4096 + dOff[h]);
      gload16u(bHi + bo, sT + 8192 + dOff[h]);
      gload16u(bLo + bo, sT + 12288 + dOff[h]);
    }
    asm volatile("s_waitcnt vmcnt(0)" ::: "memory");
    __syncthreads();
    s16x8 ah[4], al[4], bh[4], bl[4];
    #pragma unroll
    for (int f = 0; f < 4; ++f) {
      ah[f] = *(const s16x8*)&sT[offA[f]];
      al[f] = *(const s16x8*)&sT[4096 + offA[f]];
      bh[f] = *(const s16x8*)&sT[8192 + offB[f]];
      bl[f] = *(const s16x8*)&sT[12288 + offB[f]];
    }
    #pragma unroll
    for (int mf = 0; mf < 4; ++mf)
      #pragma unroll
      for (int nf = 0; nf < 4; ++nf) {
        acc[mf][nf] = __builtin_amdgcn_mfma_f32_16x16x32_bf16(ah[mf], bh[nf], acc[mf][nf], 0,0,0);
        acc[mf][nf] = __builtin_amdgcn_mfma_f32_16x16x32_bf16(ah[mf], bl[nf], acc[mf][nf], 0,0,0);
        acc[mf][nf] = __builtin_amdgcn_mfma_f32_16x16x32_bf16(al[mf], bh[nf], acc[mf][nf], 0,0,0);
      }
  }
  #pragma unroll
  for (int mf = 0; mf < 4; ++mf)
    #pragma unroll
    for (int nf = 0; nf < 4; ++nf) {
      const int n = N0 + wc*64 + nf*16 + l15;
      #pragma unroll
      for (int r = 0; r < 4; ++r) {
        const int m = M0 + wr*64 + mf*16 + kg*4 + r;
        dots[(size_t)m*NT + n] = acc[mf][nf][r];
      }
    }
}

// ---------------- Kernel 3: attention + scores ----------------
// R11 structure (algebraic cuts: no softmax normalize, no max-subtract, lambda
// folded into inv-norms). One row per 4-lane team (R8: do NOT re-batch).
__global__ __launch_bounds__(256) void attn_kernel(
    const float* __restrict__ dots, const int* __restrict__ cap_lens,
    const float* __restrict__ gI, const float* __restrict__ nI,
    const float* __restrict__ gC, const float* __restrict__ nC,
    float* __restrict__ scores, int cbase)
{
  __shared__ float sDots[LN][RTA+1];                // 48 x 73
  __shared__ __align__(16) float sGi4[TIA*RN*48];   // [2][36][48], blocks of 12 (9 valid + 3 pad)
  __shared__ __align__(16) float sGc[LN*48];        // [48][48]
  __shared__ float sColInv[TIA*RN];
  __shared__ float sRowInv[TIA*LN];
  __shared__ float sCapN[LN];
  __shared__ float sImgN[TIA*RN];
  __shared__ float sEt[TIA*LN];
  __shared__ float sEi[TIA*RN];

  const int cl = blockIdx.y;
  const int c  = cbase + cl;
  const int it = blockIdx.x;          // 0..63
  const int tid = threadIdx.x;
  const int nw = cap_lens[c];
  const float nwf = (float)nw;

  for (int idx = tid; idx < LN*RTA/4; idx += 256) {
    const int l = idx / (RTA/4), jseg = idx - l*(RTA/4);
    const float4 v = *(const float4*)(dots + ((size_t)cl*LN + l)*NT + (size_t)it*RTA + jseg*4);
    float* dst = &sDots[l][jseg*4];
    dst[0]=v.x; dst[1]=v.y; dst[2]=v.z; dst[3]=v.w;
  }
  for (int idx = tid; idx < TIA*RN*48/4; idx += 256)
    ((float4*)sGi4)[idx] = make_float4(0.f,0.f,0.f,0.f);
  for (int idx = tid; idx < 576; idx += 256) {
    const int rw = idx/12, mq = idx - rw*12;
    *(float4*)&sGc[rw*48 + mq*4] = *(const float4*)(gC + (size_t)c*LN*LN + rw*LN + mq*4);
  }
  if (tid < LN) sCapN[tid] = nC[c*LN + tid];
  if (tid < TIA*RN) sImgN[tid] = nI[it*TIA*RN + tid];
  __syncthreads();

  for (int idx = tid; idx < TIA*RN*RN; idx += 256) {
    const int i = idx / (RN*RN), rem = idx - i*(RN*RN);
    const int s = rem / RN, col = rem - s*RN;
    const int blk = col / 9, cib = col - blk*9;
    sGi4[(i*RN + s)*48 + blk*12 + cib] = gI[(size_t)(it*TIA+i)*RN*RN + rem];
  }
  if (tid < TIA*RN) {
    const int i = tid/RN, r = tid - i*RN;
    float s = 0.f;
    for (int l = 0; l < LN; ++l) { const float v = leaky(sDots[l][i*RN+r]); s += v*v; }
    sColInv[tid] = LSM * __builtin_amdgcn_rcpf(sqrtf(s) + EPSF);
  }
  if (tid < TIA*LN) {
    const int i = tid/LN, l = tid - i*LN;
    float s = 0.f;
    for (int r = 0; r < RN; ++r) { const float v = leaky(sDots[l][i*RN+r]); s += v*v; }
    sRowInv[tid] = LSM * __builtin_amdgcn_rcpf(sqrtf(s) + EPSF);
  }
  __syncthreads();

  const int team = tid >> 2, q4 = tid & 3;

  // ===== unified row loop: vrow 0..95 = t2i (i*48+l), 96..167 = i2t (i*36+r) =====
  #pragma unroll 1
  for (int pass = 0; pass < 3; ++pass) {
    const int vrow = pass*64 + team;
    if (vrow < TIA*LN) {
      // ---- t2i ----
      const int i = vrow / LN, l = vrow - i*LN;
      const int cb = i*RN + q4*9;
      float d9[9], x9[9];
      #pragma unroll
      for (int j = 0; j < 9; ++j) d9[j] = sDots[l][cb + j];
      float se = 0.f;
      #pragma unroll
      for (int j = 0; j < 9; ++j) {
        const float e = __expf(leaky(d9[j]) * sColInv[cb + j]);  // arg in [-9,9]
        x9[j] = e; se += e;
      }
      se += __shfl_xor(se, 1, 4); se += __shfl_xor(se, 2, 4);
      float ts = 0.f;
      #pragma unroll
      for (int j = 0; j < 9; ++j) {
        const float me = (x9[j]*36.f > se) ? x9[j] : 0.f;   // focal: p*36 > 1
        x9[j] = me; ts += me;
      }
      ts += __shfl_xor(ts, 1, 4); ts += __shfl_xor(ts, 2, 4);
      const float invd = __builtin_amdgcn_rcpf((ts > 0.f) ? ts : 1.f);
      float w12 = 0.f;
      #pragma unroll
      for (int j = 0; j < 9; ++j) w12 += x9[j]*d9[j];
      w12 += __shfl_xor(w12, 1, 4); w12 += __shfl_xor(w12, 2, 4);
      float qq = 0.f;
      const float* giB = sGi4 + (size_t)i*RN*48 + q4*12;
      #pragma unroll
      for (int sl = 0; sl < 4; ++sl) {
        #pragma unroll
        for (int si = 0; si < 9; ++si) {
          const float tv = __shfl(x9[si], sl, 4);
          const float4* gr = (const float4*)(giB + (sl*9 + si)*48);
          const float4 g0 = gr[0], g1 = gr[1];
          const float g8 = giB[(sl*9 + si)*48 + 8];
          const float p =
            x9[0]*g0.x + x9[1]*g0.y + x9[2]*g0.z + x9[3]*g0.w +
            x9[4]*g1.x + x9[5]*g1.y + x9[6]*g1.z + x9[7]*g1.w +
            x9[8]*g8;
          qq += tv * p;
        }
      }
      qq += __shfl_xor(qq, 1, 4); qq += __shfl_xor(qq, 2, 4);
      if (q4 == 0) {
        const float w2 = sqrtf(fmaxf(qq*invd*invd, 1e-16f));
        const float sim = (w12*invd) * __builtin_amdgcn_rcpf(fmaxf(sCapN[l]*w2, EPSF));
        sEt[vrow] = (l < nw) ? __expf(LLSE*sim) : 0.f;
      }
    } else {
      // ---- i2t ----
      const int rowid = vrow - TIA*LN;
      if (rowid < TIA*RN) {
        const int i = rowid / RN, r = rowid - i*RN;
        float d12[12], x12[12];
        #pragma unroll
        for (int j = 0; j < 12; ++j) d12[j] = sDots[q4*12+j][i*RN + r];
        float se = 0.f;
        #pragma unroll
        for (int j = 0; j < 12; ++j) {
          const int l = q4*12 + j;
          const float e = (l < nw) ? __expf(leaky(d12[j]) * sRowInv[i*LN + l]) : 0.f;
          x12[j] = e; se += e;
        }
        se += __shfl_xor(se, 1, 4); se += __shfl_xor(se, 2, 4);
        float ts = 0.f;
        #pragma unroll
        for (int j = 0; j < 12; ++j) {
          const float me = (x12[j]*nwf > se) ? x12[j] : 0.f;   // focal: p*nw > 1
          x12[j] = me; ts += me;
        }
        ts += __shfl_xor(ts, 1, 4); ts += __shfl_xor(ts, 2, 4);
        const float invd = __builtin_amdgcn_rcpf((ts > 0.f) ? ts : 1.f);
        float w12 = 0.f;
        #pragma unroll
        for (int j = 0; j < 12; ++j) w12 += x12[j]*d12[j];
        w12 += __shfl_xor(w12, 1, 4); w12 += __shfl_xor(w12, 2, 4);
        float qq = 0.f;
        const float* gcB = sGc + q4*12;
        #pragma unroll
        for (int sl = 0; sl < 4; ++sl) {
          #pragma unroll
          for (int si = 0; si < 12; ++si) {
            const float tv = __shfl(x12[si], sl, 4);
            const float4* gr = (const float4*)(gcB + (sl*12 + si)*48);
            const float4 g0 = gr[0], g1 = gr[1], g2 = gr[2];
            const float p =
              x12[0]*g0.x + x12[1]*g0.y + x12[2]*g0.z + x12[3]*g0.w +
              x12[4]*g1.x + x12[5]*g1.y + x12[6]*g1.z + x12[7]*g1.w +
              x12[8]*g2.x + x12[9]*g2.y + x12[10]*g2.z + x12[11]*g2.w;
            qq += tv * p;
          }
        }
        qq += __shfl_xor(qq, 1, 4); qq += __shfl_xor(qq, 2, 4);
        if (q4 == 0) {
          const float w2 = sqrtf(fmaxf(qq*invd*invd, 1e-16f));
          const float sim = (w12*invd) * __builtin_amdgcn_rcpf(fmaxf(sImgN[rowid]*w2, EPSF));
          sEi[rowid] = __expf(LLSE*sim);
        }
      }
    }
  }
  __syncthreads();
  if (tid < TIA) {
    float st = 0.f, si2 = 0.f;
    for (int l = 0; l < LN; ++l) st += sEt[tid*LN + l];
    for (int r = 0; r < RN; ++r) si2 += sEi[tid*RN + r];
    scores[(size_t)(it*TIA + tid)*CN + c] = __logf(st)/LLSE + __logf(si2)/LLSE;
  }
}

// ---------------- Kernel 4: margin ranking loss ----------------
__global__ __launch_bounds__(128) void loss_kernel(
    const float* __restrict__ S, float* __restrict__ out)
{
  __shared__ float red[128];
  const int t = threadIdx.x;
  const float d = S[t*CN + t];
  float m1 = -1e30f, m2 = -1e30f;
  for (int cc = 0; cc < CN; ++cc)
    if (cc != t) m1 = fmaxf(m1, 0.2f + S[t*CN+cc] - d);
  for (int i2 = 0; i2 < INN; ++i2)
    if (i2 != t) m2 = fmaxf(m2, 0.2f + S[i2*CN+t] - d);
  red[t] = fmaxf(m1, 0.f) + fmaxf(m2, 0.f);
  __syncthreads();
  for (int s = 64; s > 0; s >>= 1) {
    if (t < s) red[t] += red[t+s];
    __syncthreads();
  }
  if (t == 0) out[0] = red[0];
}

extern "C" void kernel_launch(void* const* d_in, const int* in_sizes, int n_in,
                              void* d_out, int out_size, void* d_ws, size_t ws_size,
                              hipStream_t stream) {
  (void)in_sizes; (void)n_in; (void)out_size;
  const float* imgs = (const float*)d_in[0];
  const float* caps = (const float*)d_in[1];
  const int*   lens = (const int*)d_in[2];

  const size_t bfUS = 2*((size_t)MT + NT)*DN;
  const size_t smallF = (size_t)INN*RN*RN + INN*RN + (size_t)CN*LN*LN + CN*LN + (size_t)INN*CN;
  int g = CN;
  while (g > 8) {
    const size_t need = bfUS*2 + (smallF + (size_t)g*LN*NT)*4;
    if (need <= ws_size) break;
    g >>= 1;
  }

  ushort* aHi = (ushort*)d_ws;
  ushort* aLo = aHi + (size_t)MT*DN;
  ushort* bHi = aLo + (size_t)MT*DN;
  ushort* bLo = bHi + (size_t)NT*DN;
  float* fbase = (float*)(bLo + (size_t)NT*DN);
  float* gI     = fbase;
  float* nI     = gI + (size_t)INN*RN*RN;
  float* gC     = nI + (size_t)INN*RN;
  float* nC     = gC + (size_t)CN*LN*LN;
  float* scores = nC + (size_t)CN*LN;
  float* dots   = scores + (size_t)INN*CN;

  gram_conv_kernel<<<dim3(INN+CN), dim3(256), 0, stream>>>(
      imgs, caps, gI, nI, gC, nC, aHi, aLo, bHi, bLo);
  for (int c0 = 0; c0 < CN; c0 += g) {
    dots_gemm_mfma<<<dim3(NT/128, g*LN/128), dim3(256), 0, stream>>>(
        aHi, aLo, bHi, bLo, dots, c0*LN);
    attn_kernel<<<dim3(INN/TIA, g), dim3(256), 0, stream>>>(
        dots, lens, gI, nI, gC, nC, scores, c0);
  }
  loss_kernel<<<dim3(1), dim3(128), 0, stream>>>(scores, (float*)d_out);
}

// Round 13
// 430.761 us; speedup vs baseline: 3.1833x; 1.0217x over previous
//
#include <hip/hip_runtime.h>
#include <math.h>

#define CN 128   // captions
#define INN 128  // images
#define LN 48    // words
#define RN 36    // regions
#define DN 1024  // feature dim
#define TIA 1    // images per attn block (R13: 24.3KB LDS -> 6 blocks/CU)
#define RTA (TIA*RN)   // 36
#define MT 6144  // CN*LN
#define NT 4608  // INN*RN
#define EPSF 1e-8f
#define LSM 9.0f
#define LLSE 6.0f

__device__ __forceinline__ float leaky(float x){ return x > 0.f ? x : 0.1f*x; }
__device__ __forceinline__ float dot4(float4 a, float4 b){
  return a.x*b.x + a.y*b.y + a.z*b.z + a.w*b.w;
}

typedef const __attribute__((address_space(1))) unsigned int* gp_t;
typedef __attribute__((address_space(3))) unsigned int* lp_t;
__device__ __forceinline__ void gload16u(const ushort* g, ushort* l) {
  __builtin_amdgcn_global_load_lds((gp_t)g, (lp_t)l, 16, 0, 0);
}

typedef short s16x8 __attribute__((ext_vector_type(8)));
typedef float f32x4 __attribute__((ext_vector_type(4)));

// RNE fp32 -> (hi, lo) bf16 pair
__device__ __forceinline__ void bf16split(float f, ushort& h, ushort& l) {
  const unsigned u = __float_as_uint(f);
  h = (ushort)((u + 0x7fffu + ((u>>16)&1u)) >> 16);
  const float res = f - __uint_as_float((unsigned)h << 16);
  const unsigned u2 = __float_as_uint(res);
  l = (ushort)((u2 + 0x7fffu + ((u2>>16)&1u)) >> 16);
}

// ---------------- Kernel 1: Gram matrices + norms + FUSED bf16 hi/lo emission ----------
__global__ __launch_bounds__(256) void gram_conv_kernel(
    const float* __restrict__ imgs, const float* __restrict__ caps,
    float* __restrict__ gI, float* __restrict__ nI,
    float* __restrict__ gC, float* __restrict__ nC,
    ushort* __restrict__ aHi, ushort* __restrict__ aLo,
    ushort* __restrict__ bHi, ushort* __restrict__ bLo)
{
  __shared__ __align__(16) float L[LN*132];   // max 48 rows x 132
  const int b = blockIdx.x, tid = threadIdx.x;
  if (b < INN) {
    const float* base = imgs + (size_t)b*RN*DN;
    const int rg = tid/12, cg = tid - (tid/12)*12;   // 18x12 teams, 216 active
    const bool active = tid < 216;
    float a[2][3];
    #pragma unroll
    for (int u = 0; u < 2; ++u)
      #pragma unroll
      for (int v = 0; v < 3; ++v) a[u][v] = 0.f;
    for (int d0 = 0; d0 < DN; d0 += 128) {
      __syncthreads();
      for (int idx = tid; idx < RN*32; idx += 256) {
        const int row = idx >> 5, ch = idx & 31;
        *(float4*)&L[row*132 + ch*4] = *(const float4*)(base + row*DN + d0 + ch*4);
      }
      __syncthreads();
      for (int idx = tid; idx < RN*32; idx += 256) {
        const int row = idx >> 5, ch = idx & 31;
        const float4 v = *(const float4*)&L[row*132 + ch*4];
        const float fv[4] = {v.x,v.y,v.z,v.w};
        ushort hh[4], ll[4];
        #pragma unroll
        for (int e = 0; e < 4; ++e) bf16split(fv[e], hh[e], ll[e]);
        const size_t off = (size_t)(b*RN + row)*DN + d0 + ch*4;
        *(ushort4*)(bHi + off) = make_ushort4(hh[0],hh[1],hh[2],hh[3]);
        *(ushort4*)(bLo + off) = make_ushort4(ll[0],ll[1],ll[2],ll[3]);
      }
      if (active) {
        const float* r0 = &L[(2*rg)*132],   * r1 = &L[(2*rg+1)*132];
        const float* c0 = &L[(3*cg)*132],   * c1 = &L[(3*cg+1)*132], * c2 = &L[(3*cg+2)*132];
        #pragma unroll
        for (int k = 0; k < 32; ++k) {
          const float4 x0 = *(const float4*)(r0 + k*4);
          const float4 x1 = *(const float4*)(r1 + k*4);
          const float4 y0 = *(const float4*)(c0 + k*4);
          const float4 y1 = *(const float4*)(c1 + k*4);
          const float4 y2 = *(const float4*)(c2 + k*4);
          a[0][0] += dot4(x0,y0); a[0][1] += dot4(x0,y1); a[0][2] += dot4(x0,y2);
          a[1][0] += dot4(x1,y0); a[1][1] += dot4(x1,y1); a[1][2] += dot4(x1,y2);
        }
      }
    }
    if (active) {
      float* gb = gI + (size_t)b*RN*RN;
      #pragma unroll
      for (int u = 0; u < 2; ++u)
        #pragma unroll
        for (int v = 0; v < 3; ++v) {
          const int r = 2*rg + u, s = 3*cg + v;
          gb[r*RN + s] = a[u][v];
          if (r == s) nI[b*RN + r] = sqrtf(fmaxf(a[u][v], 1e-16f));
        }
    }
  } else {
    const int c = b - INN;
    const float* base = caps + (size_t)c*LN*DN;
    const int rg = tid >> 4, cg = tid & 15;          // 16x16 teams, all 256 active
    float a[3][3];
    #pragma unroll
    for (int u = 0; u < 3; ++u)
      #pragma unroll
      for (int v = 0; v < 3; ++v) a[u][v] = 0.f;
    for (int d0 = 0; d0 < DN; d0 += 128) {
      __syncthreads();
      for (int idx = tid; idx < LN*32; idx += 256) {
        const int row = idx >> 5, ch = idx & 31;
        *(float4*)&L[row*132 + ch*4] = *(const float4*)(base + row*DN + d0 + ch*4);
      }
      __syncthreads();
      for (int idx = tid; idx < LN*32; idx += 256) {
        const int row = idx >> 5, ch = idx & 31;
        const float4 v = *(const float4*)&L[row*132 + ch*4];
        const float fv[4] = {v.x,v.y,v.z,v.w};
        ushort hh[4], ll[4];
        #pragma unroll
        for (int e = 0; e < 4; ++e) bf16split(fv[e], hh[e], ll[e]);
        const size_t off = (size_t)(c*LN + row)*DN + d0 + ch*4;
        *(ushort4*)(aHi + off) = make_ushort4(hh[0],hh[1],hh[2],hh[3]);
        *(ushort4*)(aLo + off) = make_ushort4(ll[0],ll[1],ll[2],ll[3]);
      }
      const float* r0 = &L[(3*rg)*132],   * r1 = &L[(3*rg+1)*132], * r2 = &L[(3*rg+2)*132];
      const float* c0 = &L[(3*cg)*132],   * c1 = &L[(3*cg+1)*132], * c2 = &L[(3*cg+2)*132];
      #pragma unroll
      for (int k = 0; k < 32; ++k) {
        const float4 x0 = *(const float4*)(r0 + k*4);
        const float4 x1 = *(const float4*)(r1 + k*4);
        const float4 x2 = *(const float4*)(r2 + k*4);
        const float4 y0 = *(const float4*)(c0 + k*4);
        const float4 y1 = *(const float4*)(c1 + k*4);
        const float4 y2 = *(const float4*)(c2 + k*4);
        a[0][0] += dot4(x0,y0); a[0][1] += dot4(x0,y1); a[0][2] += dot4(x0,y2);
        a[1][0] += dot4(x1,y0); a[1][1] += dot4(x1,y1); a[1][2] += dot4(x1,y2);
        a[2][0] += dot4(x2,y0); a[2][1] += dot4(x2,y1); a[2][2] += dot4(x2,y2);
      }
    }
    float* gb = gC + (size_t)c*LN*LN;
    #pragma unroll
    for (int u = 0; u < 3; ++u)
      #pragma unroll
      for (int v = 0; v < 3; ++v) {
        const int r = 3*rg + u, s = 3*cg + v;
        gb[r*LN + s] = a[u][v];
        if (r == s) nC[c*LN + r] = sqrtf(fmaxf(a[u][v], 1e-16f));
      }
  }
}

// ---------------- Kernel 2: dots GEMM via bf16x3 MFMA ----------------
__global__ __launch_bounds__(256) void dots_gemm_mfma(
    const ushort* __restrict__ aHi, const ushort* __restrict__ aLo,
    const ushort* __restrict__ bHi, const ushort* __restrict__ bLo,
    float* __restrict__ dots, int arow0)
{
  __shared__ __align__(16) ushort sT[16384];   // Ah Al Bh Bl, 8KB each
  const int tid = threadIdx.x;
  const int wv = tid >> 6, lane = tid & 63;
  const int l15 = lane & 15, kg = lane >> 4;
  const int wr = wv >> 1, wc = wv & 1;
  const int M0 = blockIdx.y * 128;
  const int N0 = blockIdx.x * 128;

  int offA[4], offB[4];
  #pragma unroll
  for (int f = 0; f < 4; ++f) {
    const int rA = wr*64 + f*16 + l15;
    offA[f] = rA*32 + ((kg ^ ((rA>>1)&3)) << 3);
    const int rB = wc*64 + f*16 + l15;
    offB[f] = rB*32 + ((kg ^ ((rB>>1)&3)) << 3);
  }
  int srow[2], sgk[2]; unsigned dOff[2];
  #pragma unroll
  for (int h = 0; h < 2; ++h) {
    const int ch = h*256 + wv*64 + lane;
    const int row = ch >> 2, gp = ch & 3;
    srow[h] = row;
    sgk[h] = (gp ^ ((row>>1)&3)) * 8;
    dOff[h] = (unsigned)(h*256 + wv*64) * 8;
  }

  f32x4 acc[4][4];
  #pragma unroll
  for (int mf = 0; mf < 4; ++mf)
    #pragma unroll
    for (int nf = 0; nf < 4; ++nf) acc[mf][nf] = (f32x4){0.f,0.f,0.f,0.f};

  const size_t aR = (size_t)(arow0 + M0);
  for (int k0 = 0; k0 < DN; k0 += 32) {
    __syncthreads();
    #pragma unroll
    for (int h = 0; h < 2; ++h) {
      const size_t ao = (aR + srow[h])*DN + k0 + sgk[h];
      const size_t bo = ((size_t)(N0 + srow[h]))*DN + k0 + sgk[h];
      gload16u(aHi + ao, sT + dOff[h]);
      gload16u(aLo + ao, sT + 4096 + dOff[h]);
      gload16u(bHi + bo, sT + 8192 + dOff[h]);
      gload16u(bLo + bo, sT + 12288 + dOff[h]);
    }
    asm volatile("s_waitcnt vmcnt(0)" ::: "memory");
    __syncthreads();
    s16x8 ah[4], al[4], bh[4], bl[4];
    #pragma unroll
    for (int f = 0; f < 4; ++f) {
      ah[f] = *(const s16x8*)&sT[offA[f]];
      al[f] = *(const s16x8*)&sT[4096 + offA[f]];
      bh[f] = *(const s16x8*)&sT[8192 + offB[f]];
      bl[f] = *(const s16x8*)&sT[12288 + offB[f]];
    }
    #pragma unroll
    for (int mf = 0; mf < 4; ++mf)
      #pragma unroll
      for (int nf = 0; nf < 4; ++nf) {
        acc[mf][nf] = __builtin_amdgcn_mfma_f32_16x16x32_bf16(ah[mf], bh[nf], acc[mf][nf], 0,0,0);
        acc[mf][nf] = __builtin_amdgcn_mfma_f32_16x16x32_bf16(ah[mf], bl[nf], acc[mf][nf], 0,0,0);
        acc[mf][nf] = __builtin_amdgcn_mfma_f32_16x16x32_bf16(al[mf], bh[nf], acc[mf][nf], 0,0,0);
      }
  }
  #pragma unroll
  for (int mf = 0; mf < 4; ++mf)
    #pragma unroll
    for (int nf = 0; nf < 4; ++nf) {
      const int n = N0 + wc*64 + nf*16 + l15;
      #pragma unroll
      for (int r = 0; r < 4; ++r) {
        const int m = M0 + wr*64 + mf*16 + kg*4 + r;
        dots[(size_t)m*NT + n] = acc[mf][nf][r];
      }
    }
}

// ---------------- Kernel 3: attention + scores ----------------
// R13: TIA=1 — LDS ~24.3KB -> 6 blocks/CU (75% occ cap). 84 vrows over 2
// passes; pass-0 boundary (vrow 48) is wave-aligned; pass-1 waves with no
// active teams branch over (execz). R11 algebraic cuts retained.
// R8 lesson stands: one row per 4-lane team, do NOT re-batch rows.
__global__ __launch_bounds__(256) void attn_kernel(
    const float* __restrict__ dots, const int* __restrict__ cap_lens,
    const float* __restrict__ gI, const float* __restrict__ nI,
    const float* __restrict__ gC, const float* __restrict__ nC,
    float* __restrict__ scores, int cbase)
{
  __shared__ float sDots[LN][RTA+1];                // 48 x 37
  __shared__ __align__(16) float sGi4[RN*48];       // [36][48], blocks of 12 (9 valid + 3 pad)
  __shared__ __align__(16) float sGc[LN*48];        // [48][48]
  __shared__ float sColInv[RN];
  __shared__ float sRowInv[LN];
  __shared__ float sCapN[LN];
  __shared__ float sImgN[RN];
  __shared__ float sEt[LN];
  __shared__ float sEi[RN];

  const int cl = blockIdx.y;
  const int c  = cbase + cl;
  const int it = blockIdx.x;          // 0..127 (= image index)
  const int tid = threadIdx.x;
  const int nw = cap_lens[c];
  const float nwf = (float)nw;

  for (int idx = tid; idx < LN*RTA/4; idx += 256) {
    const int l = idx / (RTA/4), jseg = idx - l*(RTA/4);
    const float4 v = *(const float4*)(dots + ((size_t)cl*LN + l)*NT + (size_t)it*RTA + jseg*4);
    float* dst = &sDots[l][jseg*4];
    dst[0]=v.x; dst[1]=v.y; dst[2]=v.z; dst[3]=v.w;
  }
  for (int idx = tid; idx < RN*48/4; idx += 256)
    ((float4*)sGi4)[idx] = make_float4(0.f,0.f,0.f,0.f);
  for (int idx = tid; idx < 576; idx += 256) {
    const int rw = idx/12, mq = idx - rw*12;
    *(float4*)&sGc[rw*48 + mq*4] = *(const float4*)(gC + (size_t)c*LN*LN + rw*LN + mq*4);
  }
  if (tid < LN) sCapN[tid] = nC[c*LN + tid];
  if (tid < RN) sImgN[tid] = nI[it*RN + tid];
  __syncthreads();

  for (int idx = tid; idx < RN*RN; idx += 256) {
    const int s = idx / RN, col = idx - s*RN;
    const int blk = col / 9, cib = col - blk*9;
    sGi4[s*48 + blk*12 + cib] = gI[(size_t)it*RN*RN + idx];
  }
  if (tid < RN) {
    const int r = tid;
    float s = 0.f;
    for (int l = 0; l < LN; ++l) { const float v = leaky(sDots[l][r]); s += v*v; }
    sColInv[tid] = LSM * __builtin_amdgcn_rcpf(sqrtf(s) + EPSF);
  }
  if (tid < LN) {
    const int l = tid;
    float s = 0.f;
    for (int r = 0; r < RN; ++r) { const float v = leaky(sDots[l][r]); s += v*v; }
    sRowInv[tid] = LSM * __builtin_amdgcn_rcpf(sqrtf(s) + EPSF);
  }
  __syncthreads();

  const int team = tid >> 2, q4 = tid & 3;

  // ===== unified row loop: vrow 0..47 = t2i (word l), 48..83 = i2t (region r) =====
  #pragma unroll 1
  for (int pass = 0; pass < 2; ++pass) {
    const int vrow = pass*64 + team;
    if (vrow < LN) {
      // ---- t2i ----
      const int l = vrow;
      const int cb = q4*9;
      float d9[9], x9[9];
      #pragma unroll
      for (int j = 0; j < 9; ++j) d9[j] = sDots[l][cb + j];
      float se = 0.f;
      #pragma unroll
      for (int j = 0; j < 9; ++j) {
        const float e = __expf(leaky(d9[j]) * sColInv[cb + j]);  // arg in [-9,9]
        x9[j] = e; se += e;
      }
      se += __shfl_xor(se, 1, 4); se += __shfl_xor(se, 2, 4);
      float ts = 0.f;
      #pragma unroll
      for (int j = 0; j < 9; ++j) {
        const float me = (x9[j]*36.f > se) ? x9[j] : 0.f;   // focal: p*36 > 1
        x9[j] = me; ts += me;
      }
      ts += __shfl_xor(ts, 1, 4); ts += __shfl_xor(ts, 2, 4);
      const float invd = __builtin_amdgcn_rcpf((ts > 0.f) ? ts : 1.f);
      float w12 = 0.f;
      #pragma unroll
      for (int j = 0; j < 9; ++j) w12 += x9[j]*d9[j];
      w12 += __shfl_xor(w12, 1, 4); w12 += __shfl_xor(w12, 2, 4);
      float qq = 0.f;
      const float* giB = sGi4 + q4*12;
      #pragma unroll
      for (int sl = 0; sl < 4; ++sl) {
        #pragma unroll
        for (int si = 0; si < 9; ++si) {
          const float tv = __shfl(x9[si], sl, 4);
          const float4* gr = (const float4*)(giB + (sl*9 + si)*48);
          const float4 g0 = gr[0], g1 = gr[1];
          const float g8 = giB[(sl*9 + si)*48 + 8];
          const float p =
            x9[0]*g0.x + x9[1]*g0.y + x9[2]*g0.z + x9[3]*g0.w +
            x9[4]*g1.x + x9[5]*g1.y + x9[6]*g1.z + x9[7]*g1.w +
            x9[8]*g8;
          qq += tv * p;
        }
      }
      qq += __shfl_xor(qq, 1, 4); qq += __shfl_xor(qq, 2, 4);
      if (q4 == 0) {
        const float w2 = sqrtf(fmaxf(qq*invd*invd, 1e-16f));
        const float sim = (w12*invd) * __builtin_amdgcn_rcpf(fmaxf(sCapN[l]*w2, EPSF));
        sEt[vrow] = (l < nw) ? __expf(LLSE*sim) : 0.f;
      }
    } else {
      // ---- i2t ----
      const int rowid = vrow - LN;
      if (rowid < RN) {
        const int r = rowid;
        float d12[12], x12[12];
        #pragma unroll
        for (int j = 0; j < 12; ++j) d12[j] = sDots[q4*12+j][r];
        float se = 0.f;
        #pragma unroll
        for (int j = 0; j < 12; ++j) {
          const int l = q4*12 + j;
          const float e = (l < nw) ? __expf(leaky(d12[j]) * sRowInv[l]) : 0.f;
          x12[j] = e; se += e;
        }
        se += __shfl_xor(se, 1, 4); se += __shfl_xor(se, 2, 4);
        float ts = 0.f;
        #pragma unroll
        for (int j = 0; j < 12; ++j) {
          const float me = (x12[j]*nwf > se) ? x12[j] : 0.f;   // focal: p*nw > 1
          x12[j] = me; ts += me;
        }
        ts += __shfl_xor(ts, 1, 4); ts += __shfl_xor(ts, 2, 4);
        const float invd = __builtin_amdgcn_rcpf((ts > 0.f) ? ts : 1.f);
        float w12 = 0.f;
        #pragma unroll
        for (int j = 0; j < 12; ++j) w12 += x12[j]*d12[j];
        w12 += __shfl_xor(w12, 1, 4); w12 += __shfl_xor(w12, 2, 4);
        float qq = 0.f;
        const float* gcB = sGc + q4*12;
        #pragma unroll
        for (int sl = 0; sl < 4; ++sl) {
          #pragma unroll
          for (int si = 0; si < 12; ++si) {
            const float tv = __shfl(x12[si], sl, 4);
            const float4* gr = (const float4*)(gcB + (sl*12 + si)*48);
            const float4 g0 = gr[0], g1 = gr[1], g2 = gr[2];
            const float p =
              x12[0]*g0.x + x12[1]*g0.y + x12[2]*g0.z + x12[3]*g0.w +
              x12[4]*g1.x + x12[5]*g1.y + x12[6]*g1.z + x12[7]*g1.w +
              x12[8]*g2.x + x12[9]*g2.y + x12[10]*g2.z + x12[11]*g2.w;
            qq += tv * p;
          }
        }
        qq += __shfl_xor(qq, 1, 4); qq += __shfl_xor(qq, 2, 4);
        if (q4 == 0) {
          const float w2 = sqrtf(fmaxf(qq*invd*invd, 1e-16f));
          const float sim = (w12*invd) * __builtin_amdgcn_rcpf(fmaxf(sImgN[r]*w2, EPSF));
          sEi[r] = __expf(LLSE*sim);
        }
      }
    }
  }
  __syncthreads();
  if (tid == 0) {
    float st = 0.f, si2 = 0.f;
    for (int l = 0; l < LN; ++l) st += sEt[l];
    for (int r = 0; r < RN; ++r) si2 += sEi[r];
    scores[(size_t)it*CN + c] = __logf(st)/LLSE + __logf(si2)/LLSE;
  }
}

// ---------------- Kernel 4: margin ranking loss ----------------
__global__ __launch_bounds__(128) void loss_kernel(
    const float* __restrict__ S, float* __restrict__ out)
{
  __shared__ float red[128];
  const int t = threadIdx.x;
  const float d = S[t*CN + t];
  float m1 = -1e30f, m2 = -1e30f;
  for (int cc = 0; cc < CN; ++cc)
    if (cc != t) m1 = fmaxf(m1, 0.2f + S[t*CN+cc] - d);
  for (int i2 = 0; i2 < INN; ++i2)
    if (i2 != t) m2 = fmaxf(m2, 0.2f + S[i2*CN+t] - d);
  red[t] = fmaxf(m1, 0.f) + fmaxf(m2, 0.f);
  __syncthreads();
  for (int s = 64; s > 0; s >>= 1) {
    if (t < s) red[t] += red[t+s];
    __syncthreads();
  }
  if (t == 0) out[0] = red[0];
}

extern "C" void kernel_launch(void* const* d_in, const int* in_sizes, int n_in,
                              void* d_out, int out_size, void* d_ws, size_t ws_size,
                              hipStream_t stream) {
  (void)in_sizes; (void)n_in; (void)out_size;
  const float* imgs = (const float*)d_in[0];
  const float* caps = (const float*)d_in[1];
  const int*   lens = (const int*)d_in[2];

  const size_t bfUS = 2*((size_t)MT + NT)*DN;
  const size_t smallF = (size_t)INN*RN*RN + INN*RN + (size_t)CN*LN*LN + CN*LN + (size_t)INN*CN;
  int g = CN;
  while (g > 8) {
    const size_t need = bfUS*2 + (smallF + (size_t)g*LN*NT)*4;
    if (need <= ws_size) break;
    g >>= 1;
  }

  ushort* aHi = (ushort*)d_ws;
  ushort* aLo = aHi + (size_t)MT*DN;
  ushort* bHi = aLo + (size_t)MT*DN;
  ushort* bLo = bHi + (size_t)NT*DN;
  float* fbase = (float*)(bLo + (size_t)NT*DN);
  float* gI     = fbase;
  float* nI     = gI + (size_t)INN*RN*RN;
  float* gC     = nI + (size_t)INN*RN;
  float* nC     = gC + (size_t)CN*LN*LN;
  float* scores = nC + (size_t)CN*LN;
  float* dots   = scores + (size_t)INN*CN;

  gram_conv_kernel<<<dim3(INN+CN), dim3(256), 0, stream>>>(
      imgs, caps, gI, nI, gC, nC, aHi, aLo, bHi, bLo);
  for (int c0 = 0; c0 < CN; c0 += g) {
    dots_gemm_mfma<<<dim3(NT/128, g*LN/128), dim3(256), 0, stream>>>(
        aHi, aLo, bHi, bLo, dots, c0*LN);
    attn_kernel<<<dim3(INN/TIA, g), dim3(256), 0, stream>>>(
        dots, lens, gI, nI, gC, nC, scores, c0);
  }
  loss_kernel<<<dim3(1), dim3(128), 0, stream>>>(scores, (float*)d_out);
}

// Round 14
// 390.469 us; speedup vs baseline: 3.5118x; 1.1032x over previous
//
#include <hip/hip_runtime.h>
#include <math.h>

#define CN 128   // captions
#define INN 128  // images
#define LN 48    // words
#define RN 36    // regions
#define DN 1024  // feature dim
#define TIA 1    // images per attn block (24.3KB LDS -> 6 blocks/CU)
#define RTA (TIA*RN)   // 36
#define MT 6144  // CN*LN
#define NT 4608  // INN*RN
#define EPSF 1e-8f
#define LSM 9.0f
#define LLSE 6.0f

__device__ __forceinline__ float leaky(float x){ return x > 0.f ? x : 0.1f*x; }
__device__ __forceinline__ float dot4(float4 a, float4 b){
  return a.x*b.x + a.y*b.y + a.z*b.z + a.w*b.w;
}

typedef const __attribute__((address_space(1))) unsigned int* gp_t;
typedef __attribute__((address_space(3))) unsigned int* lp_t;
__device__ __forceinline__ void gload16u(const ushort* g, ushort* l) {
  __builtin_amdgcn_global_load_lds((gp_t)g, (lp_t)l, 16, 0, 0);
}

typedef short s16x8 __attribute__((ext_vector_type(8)));
typedef float f32x4 __attribute__((ext_vector_type(4)));

// RNE fp32 -> (hi, lo) bf16 pair
__device__ __forceinline__ void bf16split(float f, ushort& h, ushort& l) {
  const unsigned u = __float_as_uint(f);
  h = (ushort)((u + 0x7fffu + ((u>>16)&1u)) >> 16);
  const float res = f - __uint_as_float((unsigned)h << 16);
  const unsigned u2 = __float_as_uint(res);
  l = (ushort)((u2 + 0x7fffu + ((u2>>16)&1u)) >> 16);
}
__device__ __forceinline__ ushort bf16rne(float f) {
  const unsigned u = __float_as_uint(f);
  return (ushort)((u + 0x7fffu + ((u>>16)&1u)) >> 16);
}

// ---------------- Kernel 1: Gram matrices + norms + FUSED bf16 emission ----------
// R14: caption-lo (aLo) plane no longer consumed by the GEMM (bf16x2 scheme
// dots ~= ah*(bh+bl)); its emission removed. Images still emit hi+lo.
__global__ __launch_bounds__(256) void gram_conv_kernel(
    const float* __restrict__ imgs, const float* __restrict__ caps,
    float* __restrict__ gI, float* __restrict__ nI,
    float* __restrict__ gC, float* __restrict__ nC,
    ushort* __restrict__ aHi,
    ushort* __restrict__ bHi, ushort* __restrict__ bLo)
{
  __shared__ __align__(16) float L[LN*132];   // max 48 rows x 132
  const int b = blockIdx.x, tid = threadIdx.x;
  if (b < INN) {
    const float* base = imgs + (size_t)b*RN*DN;
    const int rg = tid/12, cg = tid - (tid/12)*12;   // 18x12 teams, 216 active
    const bool active = tid < 216;
    float a[2][3];
    #pragma unroll
    for (int u = 0; u < 2; ++u)
      #pragma unroll
      for (int v = 0; v < 3; ++v) a[u][v] = 0.f;
    for (int d0 = 0; d0 < DN; d0 += 128) {
      __syncthreads();
      for (int idx = tid; idx < RN*32; idx += 256) {
        const int row = idx >> 5, ch = idx & 31;
        *(float4*)&L[row*132 + ch*4] = *(const float4*)(base + row*DN + d0 + ch*4);
      }
      __syncthreads();
      for (int idx = tid; idx < RN*32; idx += 256) {
        const int row = idx >> 5, ch = idx & 31;
        const float4 v = *(const float4*)&L[row*132 + ch*4];
        const float fv[4] = {v.x,v.y,v.z,v.w};
        ushort hh[4], ll[4];
        #pragma unroll
        for (int e = 0; e < 4; ++e) bf16split(fv[e], hh[e], ll[e]);
        const size_t off = (size_t)(b*RN + row)*DN + d0 + ch*4;
        *(ushort4*)(bHi + off) = make_ushort4(hh[0],hh[1],hh[2],hh[3]);
        *(ushort4*)(bLo + off) = make_ushort4(ll[0],ll[1],ll[2],ll[3]);
      }
      if (active) {
        const float* r0 = &L[(2*rg)*132],   * r1 = &L[(2*rg+1)*132];
        const float* c0 = &L[(3*cg)*132],   * c1 = &L[(3*cg+1)*132], * c2 = &L[(3*cg+2)*132];
        #pragma unroll
        for (int k = 0; k < 32; ++k) {
          const float4 x0 = *(const float4*)(r0 + k*4);
          const float4 x1 = *(const float4*)(r1 + k*4);
          const float4 y0 = *(const float4*)(c0 + k*4);
          const float4 y1 = *(const float4*)(c1 + k*4);
          const float4 y2 = *(const float4*)(c2 + k*4);
          a[0][0] += dot4(x0,y0); a[0][1] += dot4(x0,y1); a[0][2] += dot4(x0,y2);
          a[1][0] += dot4(x1,y0); a[1][1] += dot4(x1,y1); a[1][2] += dot4(x1,y2);
        }
      }
    }
    if (active) {
      float* gb = gI + (size_t)b*RN*RN;
      #pragma unroll
      for (int u = 0; u < 2; ++u)
        #pragma unroll
        for (int v = 0; v < 3; ++v) {
          const int r = 2*rg + u, s = 3*cg + v;
          gb[r*RN + s] = a[u][v];
          if (r == s) nI[b*RN + r] = sqrtf(fmaxf(a[u][v], 1e-16f));
        }
    }
  } else {
    const int c = b - INN;
    const float* base = caps + (size_t)c*LN*DN;
    const int rg = tid >> 4, cg = tid & 15;          // 16x16 teams, all 256 active
    float a[3][3];
    #pragma unroll
    for (int u = 0; u < 3; ++u)
      #pragma unroll
      for (int v = 0; v < 3; ++v) a[u][v] = 0.f;
    for (int d0 = 0; d0 < DN; d0 += 128) {
      __syncthreads();
      for (int idx = tid; idx < LN*32; idx += 256) {
        const int row = idx >> 5, ch = idx & 31;
        *(float4*)&L[row*132 + ch*4] = *(const float4*)(base + row*DN + d0 + ch*4);
      }
      __syncthreads();
      for (int idx = tid; idx < LN*32; idx += 256) {
        const int row = idx >> 5, ch = idx & 31;
        const float4 v = *(const float4*)&L[row*132 + ch*4];
        const size_t off = (size_t)(c*LN + row)*DN + d0 + ch*4;
        *(ushort4*)(aHi + off) = make_ushort4(
            bf16rne(v.x), bf16rne(v.y), bf16rne(v.z), bf16rne(v.w));
      }
      const float* r0 = &L[(3*rg)*132],   * r1 = &L[(3*rg+1)*132], * r2 = &L[(3*rg+2)*132];
      const float* c0 = &L[(3*cg)*132],   * c1 = &L[(3*cg+1)*132], * c2 = &L[(3*cg+2)*132];
      #pragma unroll
      for (int k = 0; k < 32; ++k) {
        const float4 x0 = *(const float4*)(r0 + k*4);
        const float4 x1 = *(const float4*)(r1 + k*4);
        const float4 x2 = *(const float4*)(r2 + k*4);
        const float4 y0 = *(const float4*)(c0 + k*4);
        const float4 y1 = *(const float4*)(c1 + k*4);
        const float4 y2 = *(const float4*)(c2 + k*4);
        a[0][0] += dot4(x0,y0); a[0][1] += dot4(x0,y1); a[0][2] += dot4(x0,y2);
        a[1][0] += dot4(x1,y0); a[1][1] += dot4(x1,y1); a[1][2] += dot4(x1,y2);
        a[2][0] += dot4(x2,y0); a[2][1] += dot4(x2,y1); a[2][2] += dot4(x2,y2);
      }
    }
    float* gb = gC + (size_t)c*LN*LN;
    #pragma unroll
    for (int u = 0; u < 3; ++u)
      #pragma unroll
      for (int v = 0; v < 3; ++v) {
        const int r = 3*rg + u, s = 3*cg + v;
        gb[r*LN + s] = a[u][v];
        if (r == s) nC[c*LN + r] = sqrtf(fmaxf(a[u][v], 1e-16f));
      }
  }
}

// ---------------- Kernel 2: dots GEMM via bf16x2 MFMA ----------------
// R14: dots ~= ah*bh + ah*bl  (caption-lo pass dropped; error ~0.1% relative
// on dots, absorbed by 1.26 absmax budget). 3 planes staged (24KB LDS),
// 2 MFMA per frag pair (was 3).
__global__ __launch_bounds__(256) void dots_gemm_mfma(
    const ushort* __restrict__ aHi,
    const ushort* __restrict__ bHi, const ushort* __restrict__ bLo,
    float* __restrict__ dots, int arow0)
{
  __shared__ __align__(16) ushort sT[12288];   // Ah[0,8K)B Bh[8,16K) Bl[16,24K)
  const int tid = threadIdx.x;
  const int wv = tid >> 6, lane = tid & 63;
  const int l15 = lane & 15, kg = lane >> 4;
  const int wr = wv >> 1, wc = wv & 1;
  const int M0 = blockIdx.y * 128;
  const int N0 = blockIdx.x * 128;

  int offA[4], offB[4];
  #pragma unroll
  for (int f = 0; f < 4; ++f) {
    const int rA = wr*64 + f*16 + l15;
    offA[f] = rA*32 + ((kg ^ ((rA>>1)&3)) << 3);
    const int rB = wc*64 + f*16 + l15;
    offB[f] = rB*32 + ((kg ^ ((rB>>1)&3)) << 3);
  }
  int srow[2], sgk[2]; unsigned dOff[2];
  #pragma unroll
  for (int h = 0; h < 2; ++h) {
    const int ch = h*256 + wv*64 + lane;
    const int row = ch >> 2, gp = ch & 3;
    srow[h] = row;
    sgk[h] = (gp ^ ((row>>1)&3)) * 8;
    dOff[h] = (unsigned)(h*256 + wv*64) * 8;
  }

  f32x4 acc[4][4];
  #pragma unroll
  for (int mf = 0; mf < 4; ++mf)
    #pragma unroll
    for (int nf = 0; nf < 4; ++nf) acc[mf][nf] = (f32x4){0.f,0.f,0.f,0.f};

  const size_t aR = (size_t)(arow0 + M0);
  for (int k0 = 0; k0 < DN; k0 += 32) {
    __syncthreads();
    #pragma unroll
    for (int h = 0; h < 2; ++h) {
      const size_t ao = (aR + srow[h])*DN + k0 + sgk[h];
      const size_t bo = ((size_t)(N0 + srow[h]))*DN + k0 + sgk[h];
      gload16u(aHi + ao, sT + dOff[h]);
      gload16u(bHi + bo, sT + 4096 + dOff[h]);
      gload16u(bLo + bo, sT + 8192 + dOff[h]);
    }
    asm volatile("s_waitcnt vmcnt(0)" ::: "memory");
    __syncthreads();
    s16x8 ah[4], bh[4], bl[4];
    #pragma unroll
    for (int f = 0; f < 4; ++f) {
      ah[f] = *(const s16x8*)&sT[offA[f]];
      bh[f] = *(const s16x8*)&sT[4096 + offB[f]];
      bl[f] = *(const s16x8*)&sT[8192 + offB[f]];
    }
    #pragma unroll
    for (int mf = 0; mf < 4; ++mf)
      #pragma unroll
      for (int nf = 0; nf < 4; ++nf) {
        acc[mf][nf] = __builtin_amdgcn_mfma_f32_16x16x32_bf16(ah[mf], bh[nf], acc[mf][nf], 0,0,0);
        acc[mf][nf] = __builtin_amdgcn_mfma_f32_16x16x32_bf16(ah[mf], bl[nf], acc[mf][nf], 0,0,0);
      }
  }
  #pragma unroll
  for (int mf = 0; mf < 4; ++mf)
    #pragma unroll
    for (int nf = 0; nf < 4; ++nf) {
      const int n = N0 + wc*64 + nf*16 + l15;
      #pragma unroll
      for (int r = 0; r < 4; ++r) {
        const int m = M0 + wr*64 + mf*16 + kg*4 + r;
        dots[(size_t)m*NT + n] = acc[mf][nf][r];
      }
    }
}

// ---------------- Kernel 3: attention + scores (unchanged from R13) ----------------
__global__ __launch_bounds__(256) void attn_kernel(
    const float* __restrict__ dots, const int* __restrict__ cap_lens,
    const float* __restrict__ gI, const float* __restrict__ nI,
    const float* __restrict__ gC, const float* __restrict__ nC,
    float* __restrict__ scores, int cbase)
{
  __shared__ float sDots[LN][RTA+1];                // 48 x 37
  __shared__ __align__(16) float sGi4[RN*48];       // [36][48], blocks of 12 (9 valid + 3 pad)
  __shared__ __align__(16) float sGc[LN*48];        // [48][48]
  __shared__ float sColInv[RN];
  __shared__ float sRowInv[LN];
  __shared__ float sCapN[LN];
  __shared__ float sImgN[RN];
  __shared__ float sEt[LN];
  __shared__ float sEi[RN];

  const int cl = blockIdx.y;
  const int c  = cbase + cl;
  const int it = blockIdx.x;          // 0..127 (= image index)
  const int tid = threadIdx.x;
  const int nw = cap_lens[c];
  const float nwf = (float)nw;

  for (int idx = tid; idx < LN*RTA/4; idx += 256) {
    const int l = idx / (RTA/4), jseg = idx - l*(RTA/4);
    const float4 v = *(const float4*)(dots + ((size_t)cl*LN + l)*NT + (size_t)it*RTA + jseg*4);
    float* dst = &sDots[l][jseg*4];
    dst[0]=v.x; dst[1]=v.y; dst[2]=v.z; dst[3]=v.w;
  }
  for (int idx = tid; idx < RN*48/4; idx += 256)
    ((float4*)sGi4)[idx] = make_float4(0.f,0.f,0.f,0.f);
  for (int idx = tid; idx < 576; idx += 256) {
    const int rw = idx/12, mq = idx - rw*12;
    *(float4*)&sGc[rw*48 + mq*4] = *(const float4*)(gC + (size_t)c*LN*LN + rw*LN + mq*4);
  }
  if (tid < LN) sCapN[tid] = nC[c*LN + tid];
  if (tid < RN) sImgN[tid] = nI[it*RN + tid];
  __syncthreads();

  for (int idx = tid; idx < RN*RN; idx += 256) {
    const int s = idx / RN, col = idx - s*RN;
    const int blk = col / 9, cib = col - blk*9;
    sGi4[s*48 + blk*12 + cib] = gI[(size_t)it*RN*RN + idx];
  }
  if (tid < RN) {
    const int r = tid;
    float s = 0.f;
    for (int l = 0; l < LN; ++l) { const float v = leaky(sDots[l][r]); s += v*v; }
    sColInv[tid] = LSM * __builtin_amdgcn_rcpf(sqrtf(s) + EPSF);
  }
  if (tid < LN) {
    const int l = tid;
    float s = 0.f;
    for (int r = 0; r < RN; ++r) { const float v = leaky(sDots[l][r]); s += v*v; }
    sRowInv[tid] = LSM * __builtin_amdgcn_rcpf(sqrtf(s) + EPSF);
  }
  __syncthreads();

  const int team = tid >> 2, q4 = tid & 3;

  // ===== unified row loop: vrow 0..47 = t2i (word l), 48..83 = i2t (region r) =====
  #pragma unroll 1
  for (int pass = 0; pass < 2; ++pass) {
    const int vrow = pass*64 + team;
    if (vrow < LN) {
      // ---- t2i ----
      const int l = vrow;
      const int cb = q4*9;
      float d9[9], x9[9];
      #pragma unroll
      for (int j = 0; j < 9; ++j) d9[j] = sDots[l][cb + j];
      float se = 0.f;
      #pragma unroll
      for (int j = 0; j < 9; ++j) {
        const float e = __expf(leaky(d9[j]) * sColInv[cb + j]);  // arg in [-9,9]
        x9[j] = e; se += e;
      }
      se += __shfl_xor(se, 1, 4); se += __shfl_xor(se, 2, 4);
      float ts = 0.f;
      #pragma unroll
      for (int j = 0; j < 9; ++j) {
        const float me = (x9[j]*36.f > se) ? x9[j] : 0.f;   // focal: p*36 > 1
        x9[j] = me; ts += me;
      }
      ts += __shfl_xor(ts, 1, 4); ts += __shfl_xor(ts, 2, 4);
      const float invd = __builtin_amdgcn_rcpf((ts > 0.f) ? ts : 1.f);
      float w12 = 0.f;
      #pragma unroll
      for (int j = 0; j < 9; ++j) w12 += x9[j]*d9[j];
      w12 += __shfl_xor(w12, 1, 4); w12 += __shfl_xor(w12, 2, 4);
      float qq = 0.f;
      const float* giB = sGi4 + q4*12;
      #pragma unroll
      for (int sl = 0; sl < 4; ++sl) {
        #pragma unroll
        for (int si = 0; si < 9; ++si) {
          const float tv = __shfl(x9[si], sl, 4);
          const float4* gr = (const float4*)(giB + (sl*9 + si)*48);
          const float4 g0 = gr[0], g1 = gr[1];
          const float g8 = giB[(sl*9 + si)*48 + 8];
          const float p =
            x9[0]*g0.x + x9[1]*g0.y + x9[2]*g0.z + x9[3]*g0.w +
            x9[4]*g1.x + x9[5]*g1.y + x9[6]*g1.z + x9[7]*g1.w +
            x9[8]*g8;
          qq += tv * p;
        }
      }
      qq += __shfl_xor(qq, 1, 4); qq += __shfl_xor(qq, 2, 4);
      if (q4 == 0) {
        const float w2 = sqrtf(fmaxf(qq*invd*invd, 1e-16f));
        const float sim = (w12*invd) * __builtin_amdgcn_rcpf(fmaxf(sCapN[l]*w2, EPSF));
        sEt[vrow] = (l < nw) ? __expf(LLSE*sim) : 0.f;
      }
    } else {
      // ---- i2t ----
      const int rowid = vrow - LN;
      if (rowid < RN) {
        const int r = rowid;
        float d12[12], x12[12];
        #pragma unroll
        for (int j = 0; j < 12; ++j) d12[j] = sDots[q4*12+j][r];
        float se = 0.f;
        #pragma unroll
        for (int j = 0; j < 12; ++j) {
          const int l = q4*12 + j;
          const float e = (l < nw) ? __expf(leaky(d12[j]) * sRowInv[l]) : 0.f;
          x12[j] = e; se += e;
        }
        se += __shfl_xor(se, 1, 4); se += __shfl_xor(se, 2, 4);
        float ts = 0.f;
        #pragma unroll
        for (int j = 0; j < 12; ++j) {
          const float me = (x12[j]*nwf > se) ? x12[j] : 0.f;   // focal: p*nw > 1
          x12[j] = me; ts += me;
        }
        ts += __shfl_xor(ts, 1, 4); ts += __shfl_xor(ts, 2, 4);
        const float invd = __builtin_amdgcn_rcpf((ts > 0.f) ? ts : 1.f);
        float w12 = 0.f;
        #pragma unroll
        for (int j = 0; j < 12; ++j) w12 += x12[j]*d12[j];
        w12 += __shfl_xor(w12, 1, 4); w12 += __shfl_xor(w12, 2, 4);
        float qq = 0.f;
        const float* gcB = sGc + q4*12;
        #pragma unroll
        for (int sl = 0; sl < 4; ++sl) {
          #pragma unroll
          for (int si = 0; si < 12; ++si) {
            const float tv = __shfl(x12[si], sl, 4);
            const float4* gr = (const float4*)(gcB + (sl*12 + si)*48);
            const float4 g0 = gr[0], g1 = gr[1], g2 = gr[2];
            const float p =
              x12[0]*g0.x + x12[1]*g0.y + x12[2]*g0.z + x12[3]*g0.w +
              x12[4]*g1.x + x12[5]*g1.y + x12[6]*g1.z + x12[7]*g1.w +
              x12[8]*g2.x + x12[9]*g2.y + x12[10]*g2.z + x12[11]*g2.w;
            qq += tv * p;
          }
        }
        qq += __shfl_xor(qq, 1, 4); qq += __shfl_xor(qq, 2, 4);
        if (q4 == 0) {
          const float w2 = sqrtf(fmaxf(qq*invd*invd, 1e-16f));
          const float sim = (w12*invd) * __builtin_amdgcn_rcpf(fmaxf(sImgN[r]*w2, EPSF));
          sEi[r] = __expf(LLSE*sim);
        }
      }
    }
  }
  __syncthreads();
  if (tid == 0) {
    float st = 0.f, si2 = 0.f;
    for (int l = 0; l < LN; ++l) st += sEt[l];
    for (int r = 0; r < RN; ++r) si2 += sEi[r];
    scores[(size_t)it*CN + c] = __logf(st)/LLSE + __logf(si2)/LLSE;
  }
}

// ---------------- Kernel 4: margin ranking loss ----------------
__global__ __launch_bounds__(128) void loss_kernel(
    const float* __restrict__ S, float* __restrict__ out)
{
  __shared__ float red[128];
  const int t = threadIdx.x;
  const float d = S[t*CN + t];
  float m1 = -1e30f, m2 = -1e30f;
  for (int cc = 0; cc < CN; ++cc)
    if (cc != t) m1 = fmaxf(m1, 0.2f + S[t*CN+cc] - d);
  for (int i2 = 0; i2 < INN; ++i2)
    if (i2 != t) m2 = fmaxf(m2, 0.2f + S[i2*CN+t] - d);
  red[t] = fmaxf(m1, 0.f) + fmaxf(m2, 0.f);
  __syncthreads();
  for (int s = 64; s > 0; s >>= 1) {
    if (t < s) red[t] += red[t+s];
    __syncthreads();
  }
  if (t == 0) out[0] = red[0];
}

extern "C" void kernel_launch(void* const* d_in, const int* in_sizes, int n_in,
                              void* d_out, int out_size, void* d_ws, size_t ws_size,
                              hipStream_t stream) {
  (void)in_sizes; (void)n_in; (void)out_size;
  const float* imgs = (const float*)d_in[0];
  const float* caps = (const float*)d_in[1];
  const int*   lens = (const int*)d_in[2];

  // ws layout kept from R13 (aLo slot reserved but unused)
  const size_t bfUS = 2*((size_t)MT + NT)*DN;
  const size_t smallF = (size_t)INN*RN*RN + INN*RN + (size_t)CN*LN*LN + CN*LN + (size_t)INN*CN;
  int g = CN;
  while (g > 8) {
    const size_t need = bfUS*2 + (smallF + (size_t)g*LN*NT)*4;
    if (need <= ws_size) break;
    g >>= 1;
  }

  ushort* aHi = (ushort*)d_ws;
  ushort* aLo = aHi + (size_t)MT*DN;   // unused (R14)
  ushort* bHi = aLo + (size_t)MT*DN;
  ushort* bLo = bHi + (size_t)NT*DN;
  float* fbase = (float*)(bLo + (size_t)NT*DN);
  float* gI     = fbase;
  float* nI     = gI + (size_t)INN*RN*RN;
  float* gC     = nI + (size_t)INN*RN;
  float* nC     = gC + (size_t)CN*LN*LN;
  float* scores = nC + (size_t)CN*LN;
  float* dots   = scores + (size_t)INN*CN;

  gram_conv_kernel<<<dim3(INN+CN), dim3(256), 0, stream>>>(
      imgs, caps, gI, nI, gC, nC, aHi, bHi, bLo);
  for (int c0 = 0; c0 < CN; c0 += g) {
    dots_gemm_mfma<<<dim3(NT/128, g*LN/128), dim3(256), 0, stream>>>(
        aHi, bHi, bLo, dots, c0*LN);
    attn_kernel<<<dim3(INN/TIA, g), dim3(256), 0, stream>>>(
        dots, lens, gI, nI, gC, nC, scores, c0);
  }
  loss_kernel<<<dim3(1), dim3(128), 0, stream>>>(scores, (float*)d_out);
}

// Round 15
// 377.369 us; speedup vs baseline: 3.6337x; 1.0347x over previous
//
#include <hip/hip_runtime.h>
#include <math.h>

#define CN 128   // captions
#define INN 128  // images
#define LN 48    // words
#define RN 36    // regions
#define DN 1024  // feature dim
#define RTA 36   // regions per attn block (TIA=1)
#define MT 6144  // CN*LN
#define NT 4608  // INN*RN
#define EPSF 1e-8f
#define LSM 9.0f
#define LLSE 6.0f

__device__ __forceinline__ float leaky(float x){ return x > 0.f ? x : 0.1f*x; }
__device__ __forceinline__ float dot4(float4 a, float4 b){
  return a.x*b.x + a.y*b.y + a.z*b.z + a.w*b.w;
}

typedef const __attribute__((address_space(1))) unsigned int* gp_t;
typedef __attribute__((address_space(3))) unsigned int* lp_t;
__device__ __forceinline__ void gload16u(const ushort* g, ushort* l) {
  __builtin_amdgcn_global_load_lds((gp_t)g, (lp_t)l, 16, 0, 0);
}

typedef short s16x8 __attribute__((ext_vector_type(8)));
typedef float f32x4 __attribute__((ext_vector_type(4)));

__device__ __forceinline__ void bf16split(float f, ushort& h, ushort& l) {
  const unsigned u = __float_as_uint(f);
  h = (ushort)((u + 0x7fffu + ((u>>16)&1u)) >> 16);
  const float res = f - __uint_as_float((unsigned)h << 16);
  const unsigned u2 = __float_as_uint(res);
  l = (ushort)((u2 + 0x7fffu + ((u2>>16)&1u)) >> 16);
}
__device__ __forceinline__ ushort bf16rne(float f) {
  const unsigned u = __float_as_uint(f);
  return (ushort)((u + 0x7fffu + ((u>>16)&1u)) >> 16);
}
__device__ __forceinline__ float bf2f(ushort u) {
  return __uint_as_float((unsigned)u << 16);
}
// XOR swizzle within a 64-elem bf16 row (8-elem granules): 2-way max bank alias
__device__ __forceinline__ int swzi(int row, int col) {
  return (col & 7) | ((((col >> 3) ^ (row & 7)) & 7) << 3);
}

// ---------------- Kernel 1: Gram + norms + bf16 emission (planes + padded G) ----------
__global__ __launch_bounds__(256) void gram_conv_kernel(
    const float* __restrict__ imgs, const float* __restrict__ caps,
    float* __restrict__ gI, float* __restrict__ nI,
    float* __restrict__ gC, float* __restrict__ nC,
    ushort* __restrict__ aHi,
    ushort* __restrict__ bHi, ushort* __restrict__ bLo,
    ushort* __restrict__ gIb, ushort* __restrict__ gCb)
{
  __shared__ __align__(16) float L[LN*132];
  const int b = blockIdx.x, tid = threadIdx.x;
  if (b < INN) {
    const float* base = imgs + (size_t)b*RN*DN;
    const int rg = tid/12, cg = tid - (tid/12)*12;
    const bool active = tid < 216;
    float a[2][3];
    #pragma unroll
    for (int u = 0; u < 2; ++u)
      #pragma unroll
      for (int v = 0; v < 3; ++v) a[u][v] = 0.f;
    for (int d0 = 0; d0 < DN; d0 += 128) {
      __syncthreads();
      for (int idx = tid; idx < RN*32; idx += 256) {
        const int row = idx >> 5, ch = idx & 31;
        *(float4*)&L[row*132 + ch*4] = *(const float4*)(base + row*DN + d0 + ch*4);
      }
      __syncthreads();
      for (int idx = tid; idx < RN*32; idx += 256) {
        const int row = idx >> 5, ch = idx & 31;
        const float4 v = *(const float4*)&L[row*132 + ch*4];
        const float fv[4] = {v.x,v.y,v.z,v.w};
        ushort hh[4], ll[4];
        #pragma unroll
        for (int e = 0; e < 4; ++e) bf16split(fv[e], hh[e], ll[e]);
        const size_t off = (size_t)(b*RN + row)*DN + d0 + ch*4;
        *(ushort4*)(bHi + off) = make_ushort4(hh[0],hh[1],hh[2],hh[3]);
        *(ushort4*)(bLo + off) = make_ushort4(ll[0],ll[1],ll[2],ll[3]);
      }
      if (active) {
        const float* r0 = &L[(2*rg)*132],   * r1 = &L[(2*rg+1)*132];
        const float* c0 = &L[(3*cg)*132],   * c1 = &L[(3*cg+1)*132], * c2 = &L[(3*cg+2)*132];
        #pragma unroll
        for (int k = 0; k < 32; ++k) {
          const float4 x0 = *(const float4*)(r0 + k*4);
          const float4 x1 = *(const float4*)(r1 + k*4);
          const float4 y0 = *(const float4*)(c0 + k*4);
          const float4 y1 = *(const float4*)(c1 + k*4);
          const float4 y2 = *(const float4*)(c2 + k*4);
          a[0][0] += dot4(x0,y0); a[0][1] += dot4(x0,y1); a[0][2] += dot4(x0,y2);
          a[1][0] += dot4(x1,y0); a[1][1] += dot4(x1,y1); a[1][2] += dot4(x1,y2);
        }
      }
    }
    if (active) {
      float* gb = gI + (size_t)b*RN*RN;
      #pragma unroll
      for (int u = 0; u < 2; ++u)
        #pragma unroll
        for (int v = 0; v < 3; ++v) {
          const int r = 2*rg + u, s = 3*cg + v;
          gb[r*RN + s] = a[u][v];
          if (r == s) nI[b*RN + r] = sqrtf(fmaxf(a[u][v], 1e-16f));
        }
    }
    // emit padded bf16 G (B-layout; symmetric) from just-written fp32 (L2-hot)
    __threadfence_block();
    __syncthreads();
    const float* gsrc = gI + (size_t)b*RN*RN;
    ushort* gdst = gIb + (size_t)b*3072;
    for (int idx = tid; idx < 3072; idx += 256) {
      const int row = idx >> 6, col = idx & 63;
      gdst[idx] = (row < RN && col < RN) ? bf16rne(gsrc[row*RN + col]) : (ushort)0;
    }
  } else {
    const int c = b - INN;
    const float* base = caps + (size_t)c*LN*DN;
    const int rg = tid >> 4, cg = tid & 15;
    float a[3][3];
    #pragma unroll
    for (int u = 0; u < 3; ++u)
      #pragma unroll
      for (int v = 0; v < 3; ++v) a[u][v] = 0.f;
    for (int d0 = 0; d0 < DN; d0 += 128) {
      __syncthreads();
      for (int idx = tid; idx < LN*32; idx += 256) {
        const int row = idx >> 5, ch = idx & 31;
        *(float4*)&L[row*132 + ch*4] = *(const float4*)(base + row*DN + d0 + ch*4);
      }
      __syncthreads();
      for (int idx = tid; idx < LN*32; idx += 256) {
        const int row = idx >> 5, ch = idx & 31;
        const float4 v = *(const float4*)&L[row*132 + ch*4];
        const size_t off = (size_t)(c*LN + row)*DN + d0 + ch*4;
        *(ushort4*)(aHi + off) = make_ushort4(
            bf16rne(v.x), bf16rne(v.y), bf16rne(v.z), bf16rne(v.w));
      }
      const float* r0 = &L[(3*rg)*132],   * r1 = &L[(3*rg+1)*132], * r2 = &L[(3*rg+2)*132];
      const float* c0 = &L[(3*cg)*132],   * c1 = &L[(3*cg+1)*132], * c2 = &L[(3*cg+2)*132];
      #pragma unroll
      for (int k = 0; k < 32; ++k) {
        const float4 x0 = *(const float4*)(r0 + k*4);
        const float4 x1 = *(const float4*)(r1 + k*4);
        const float4 x2 = *(const float4*)(r2 + k*4);
        const float4 y0 = *(const float4*)(c0 + k*4);
        const float4 y1 = *(const float4*)(c1 + k*4);
        const float4 y2 = *(const float4*)(c2 + k*4);
        a[0][0] += dot4(x0,y0); a[0][1] += dot4(x0,y1); a[0][2] += dot4(x0,y2);
        a[1][0] += dot4(x1,y0); a[1][1] += dot4(x1,y1); a[1][2] += dot4(x1,y2);
        a[2][0] += dot4(x2,y0); a[2][1] += dot4(x2,y1); a[2][2] += dot4(x2,y2);
      }
    }
    float* gb = gC + (size_t)c*LN*LN;
    #pragma unroll
    for (int u = 0; u < 3; ++u)
      #pragma unroll
      for (int v = 0; v < 3; ++v) {
        const int r = 3*rg + u, s = 3*cg + v;
        gb[r*LN + s] = a[u][v];
        if (r == s) nC[c*LN + r] = sqrtf(fmaxf(a[u][v], 1e-16f));
      }
    __threadfence_block();
    __syncthreads();
    const float* gsrc = gC + (size_t)c*LN*LN;
    ushort* gdst = gCb + (size_t)c*3072;
    for (int idx = tid; idx < 3072; idx += 256) {
      const int row = idx >> 6, col = idx & 63;
      gdst[idx] = (col < LN) ? bf16rne(gsrc[row*LN + col]) : (ushort)0;
    }
  }
}

// ---------------- Kernel 2: dots GEMM via bf16x2 MFMA (unchanged R14) ----------------
__global__ __launch_bounds__(256) void dots_gemm_mfma(
    const ushort* __restrict__ aHi,
    const ushort* __restrict__ bHi, const ushort* __restrict__ bLo,
    float* __restrict__ dots, int arow0)
{
  __shared__ __align__(16) ushort sT[12288];
  const int tid = threadIdx.x;
  const int wv = tid >> 6, lane = tid & 63;
  const int l15 = lane & 15, kg = lane >> 4;
  const int wr = wv >> 1, wc = wv & 1;
  const int M0 = blockIdx.y * 128;
  const int N0 = blockIdx.x * 128;

  int offA[4], offB[4];
  #pragma unroll
  for (int f = 0; f < 4; ++f) {
    const int rA = wr*64 + f*16 + l15;
    offA[f] = rA*32 + ((kg ^ ((rA>>1)&3)) << 3);
    const int rB = wc*64 + f*16 + l15;
    offB[f] = rB*32 + ((kg ^ ((rB>>1)&3)) << 3);
  }
  int srow[2], sgk[2]; unsigned dOff[2];
  #pragma unroll
  for (int h = 0; h < 2; ++h) {
    const int ch = h*256 + wv*64 + lane;
    const int row = ch >> 2, gp = ch & 3;
    srow[h] = row;
    sgk[h] = (gp ^ ((row>>1)&3)) * 8;
    dOff[h] = (unsigned)(h*256 + wv*64) * 8;
  }

  f32x4 acc[4][4];
  #pragma unroll
  for (int mf = 0; mf < 4; ++mf)
    #pragma unroll
    for (int nf = 0; nf < 4; ++nf) acc[mf][nf] = (f32x4){0.f,0.f,0.f,0.f};

  const size_t aR = (size_t)(arow0 + M0);
  for (int k0 = 0; k0 < DN; k0 += 32) {
    __syncthreads();
    #pragma unroll
    for (int h = 0; h < 2; ++h) {
      const size_t ao = (aR + srow[h])*DN + k0 + sgk[h];
      const size_t bo = ((size_t)(N0 + srow[h]))*DN + k0 + sgk[h];
      gload16u(aHi + ao, sT + dOff[h]);
      gload16u(bHi + bo, sT + 4096 + dOff[h]);
      gload16u(bLo + bo, sT + 8192 + dOff[h]);
    }
    asm volatile("s_waitcnt vmcnt(0)" ::: "memory");
    __syncthreads();
    s16x8 ah[4], bh[4], bl[4];
    #pragma unroll
    for (int f = 0; f < 4; ++f) {
      ah[f] = *(const s16x8*)&sT[offA[f]];
      bh[f] = *(const s16x8*)&sT[4096 + offB[f]];
      bl[f] = *(const s16x8*)&sT[8192 + offB[f]];
    }
    #pragma unroll
    for (int mf = 0; mf < 4; ++mf)
      #pragma unroll
      for (int nf = 0; nf < 4; ++nf) {
        acc[mf][nf] = __builtin_amdgcn_mfma_f32_16x16x32_bf16(ah[mf], bh[nf], acc[mf][nf], 0,0,0);
        acc[mf][nf] = __builtin_amdgcn_mfma_f32_16x16x32_bf16(ah[mf], bl[nf], acc[mf][nf], 0,0,0);
      }
  }
  #pragma unroll
  for (int mf = 0; mf < 4; ++mf)
    #pragma unroll
    for (int nf = 0; nf < 4; ++nf) {
      const int n = N0 + wc*64 + nf*16 + l15;
      #pragma unroll
      for (int r = 0; r < 4; ++r) {
        const int m = M0 + wr*64 + mf*16 + kg*4 + r;
        dots[(size_t)m*NT + n] = acc[mf][nf][r];
      }
    }
}

// ---------------- Kernel 3: attention — qq via MFMA ----------------
// Phase B computes focal-masked unnormalized me rows (R11 algebra), stores bf16
// in LDS (swizzled). Phase C: H_t = Me_t x Gi, H_i = Gc x Me_i via 16x16x32
// MFMA (K padded 64, pads zeroed), elementwise H*Me + butterfly + LDS atomics.
__global__ __launch_bounds__(256) void attn_kernel(
    const float* __restrict__ dots, const int* __restrict__ cap_lens,
    const ushort* __restrict__ gIb, const ushort* __restrict__ gCb,
    const float* __restrict__ nI, const float* __restrict__ nC,
    float* __restrict__ scores, int cbase)
{
  __shared__ float sDots[LN][RTA+1];                  // 48 x 37
  __shared__ __align__(16) ushort sMeT[LN*64];        // A: [l][r] swizzled
  __shared__ __align__(16) ushort sMeIT[48*64];       // B: [r][l] swizzled
  __shared__ __align__(16) ushort sGcA[LN*64];        // A: [l][m] swizzled
  __shared__ __align__(16) ushort sGiB[48*64];        // B: [s][r] swizzled (symmetric)
  __shared__ float sQqT[LN], sQqI[48];
  __shared__ float sW12t[LN], sInvT[LN];
  __shared__ float sW12i[RN], sInvI[RN];
  __shared__ float sColInv[RN], sRowInv[LN];
  __shared__ float sCapN[LN], sImgN[RN];
  __shared__ float sEt[LN], sEi[RN];

  const int cl = blockIdx.y;
  const int c  = cbase + cl;
  const int it = blockIdx.x;
  const int tid = threadIdx.x;
  const int lane = tid & 63, wv = tid >> 6;
  const int l15 = lane & 15, kg = lane >> 4;
  const int nw = cap_lens[c];
  const float nwf = (float)nw;

  // ---- Phase A: stage ----
  for (int idx = tid; idx < LN*RTA/4; idx += 256) {
    const int l = idx / (RTA/4), jseg = idx - l*(RTA/4);
    const float4 v = *(const float4*)(dots + ((size_t)cl*LN + l)*NT + (size_t)it*RTA + jseg*4);
    float* dst = &sDots[l][jseg*4];
    dst[0]=v.x; dst[1]=v.y; dst[2]=v.z; dst[3]=v.w;
  }
  for (int idx = tid; idx < 768; idx += 256) {   // zero Me buffers (uint4 = 8 ushorts)
    ((uint4*)sMeT)[idx & 383] = make_uint4(0,0,0,0);
    if (idx < 384) ((uint4*)sMeT)[idx] = make_uint4(0,0,0,0);
    else ((uint4*)sMeIT)[idx-384] = make_uint4(0,0,0,0);
  }
  for (int idx = tid; idx < 384; idx += 256) {   // Gc copy-in, swizzled granules
    const int row = idx >> 3, gk = idx & 7;
    *(uint4*)&sGcA[row*64 + (gk ^ (row&7))*8] =
      *(const uint4*)(gCb + (size_t)c*3072 + row*64 + gk*8);
  }
  for (int idx = tid; idx < 384; idx += 256) {   // Gi copy-in, swizzled
    const int row = idx >> 3, gk = idx & 7;
    *(uint4*)&sGiB[row*64 + (gk ^ (row&7))*8] =
      *(const uint4*)(gIb + (size_t)it*3072 + row*64 + gk*8);
  }
  if (tid < LN) { sCapN[tid] = nC[c*LN + tid]; sQqT[tid] = 0.f; }
  if (tid >= 64 && tid < 64+48) sQqI[tid-64] = 0.f;
  if (tid >= 128 && tid < 128+RN) sImgN[tid-128] = nI[it*RN + (tid-128)];
  __syncthreads();

  if (tid < RN) {
    float s = 0.f;
    for (int l = 0; l < LN; ++l) { const float v = leaky(sDots[l][tid]); s += v*v; }
    sColInv[tid] = LSM * __builtin_amdgcn_rcpf(sqrtf(s) + EPSF);
  }
  if (tid >= 64 && tid < 64+LN) {
    const int l = tid - 64;
    float s = 0.f;
    for (int r = 0; r < RN; ++r) { const float v = leaky(sDots[l][r]); s += v*v; }
    sRowInv[l] = LSM * __builtin_amdgcn_rcpf(sqrtf(s) + EPSF);
  }
  __syncthreads();

  // ---- Phase B: me rows (one row per 4-lane team; R8: do NOT re-batch) ----
  const int team = tid >> 2, q4 = tid & 3;
  #pragma unroll 1
  for (int pass = 0; pass < 2; ++pass) {
    const int vrow = pass*64 + team;
    if (vrow < LN) {
      const int l = vrow;
      const int cb = q4*9;
      float d9[9], x9[9];
      #pragma unroll
      for (int j = 0; j < 9; ++j) d9[j] = sDots[l][cb + j];
      float se = 0.f;
      #pragma unroll
      for (int j = 0; j < 9; ++j) {
        const float e = __expf(leaky(d9[j]) * sColInv[cb + j]);
        x9[j] = e; se += e;
      }
      se += __shfl_xor(se, 1, 4); se += __shfl_xor(se, 2, 4);
      float ts = 0.f;
      #pragma unroll
      for (int j = 0; j < 9; ++j) {
        const float me = (x9[j]*36.f > se) ? x9[j] : 0.f;
        x9[j] = me; ts += me;
      }
      ts += __shfl_xor(ts, 1, 4); ts += __shfl_xor(ts, 2, 4);
      float w12 = 0.f;
      #pragma unroll
      for (int j = 0; j < 9; ++j) w12 += x9[j]*d9[j];
      w12 += __shfl_xor(w12, 1, 4); w12 += __shfl_xor(w12, 2, 4);
      #pragma unroll
      for (int j = 0; j < 9; ++j)
        sMeT[l*64 + swzi(l, cb + j)] = bf16rne(x9[j]);
      if (q4 == 0) {
        sW12t[l] = w12;
        sInvT[l] = __builtin_amdgcn_rcpf((ts > 0.f) ? ts : 1.f);
      }
    } else {
      const int r = vrow - LN;
      if (r < RN) {
        float d12[12], x12[12];
        #pragma unroll
        for (int j = 0; j < 12; ++j) d12[j] = sDots[q4*12+j][r];
        float se = 0.f;
        #pragma unroll
        for (int j = 0; j < 12; ++j) {
          const int l = q4*12 + j;
          const float e = (l < nw) ? __expf(leaky(d12[j]) * sRowInv[l]) : 0.f;
          x12[j] = e; se += e;
        }
        se += __shfl_xor(se, 1, 4); se += __shfl_xor(se, 2, 4);
        float ts = 0.f;
        #pragma unroll
        for (int j = 0; j < 12; ++j) {
          const float me = (x12[j]*nwf > se) ? x12[j] : 0.f;
          x12[j] = me; ts += me;
        }
        ts += __shfl_xor(ts, 1, 4); ts += __shfl_xor(ts, 2, 4);
        float w12 = 0.f;
        #pragma unroll
        for (int j = 0; j < 12; ++j) w12 += x12[j]*d12[j];
        w12 += __shfl_xor(w12, 1, 4); w12 += __shfl_xor(w12, 2, 4);
        #pragma unroll
        for (int j = 0; j < 12; ++j)
          sMeIT[r*64 + swzi(r, q4*12 + j)] = bf16rne(x12[j]);
        if (q4 == 0) {
          sW12i[r] = w12;
          sInvI[r] = __builtin_amdgcn_rcpf((ts > 0.f) ? ts : 1.f);
        }
      }
    }
  }
  __syncthreads();

  // ---- Phase C: qq via MFMA (18 tiles: 9 t2i + 9 i2t) ----
  #pragma unroll 1
  for (int t = wv; t < 18; t += 4) {
    const bool isT = (t < 9);
    const int tt = isT ? t : t - 9;
    const int mt = tt / 3, nt = tt - 3*(tt/3);
    const ushort* Ab = isT ? sMeT : sGcA;
    const ushort* Bb = isT ? sGiB : sMeIT;
    const int arow = mt*16 + l15;
    const int brow = nt*16 + l15;
    f32x4 acc = (f32x4){0.f,0.f,0.f,0.f};
    #pragma unroll
    for (int ks = 0; ks < 2; ++ks) {
      const s16x8 af = *(const s16x8*)&Ab[arow*64 + (((ks*4+kg) ^ (arow&7)))*8];
      const s16x8 bf = *(const s16x8*)&Bb[brow*64 + (((ks*4+kg) ^ (brow&7)))*8];
      acc = __builtin_amdgcn_mfma_f32_16x16x32_bf16(af, bf, acc, 0,0,0);
    }
    if (isT) {
      // H_t[l][s]: qq_t[l] += sum_s H*Me_t[l][s]
      float part[4];
      #pragma unroll
      for (int rg = 0; rg < 4; ++rg) {
        const int l = mt*16 + kg*4 + rg, s = nt*16 + l15;
        part[rg] = acc[rg] * bf2f(sMeT[l*64 + swzi(l, s)]);
      }
      #pragma unroll
      for (int o = 1; o < 16; o <<= 1)
        #pragma unroll
        for (int rg = 0; rg < 4; ++rg) part[rg] += __shfl_xor(part[rg], o, 16);
      if (l15 == 0)
        #pragma unroll
        for (int rg = 0; rg < 4; ++rg)
          atomicAdd(&sQqT[mt*16 + kg*4 + rg], part[rg]);
    } else {
      // H_i[l][r]: qq_i[r] += sum_l H*Me_i[l][r]
      float part = 0.f;
      #pragma unroll
      for (int rg = 0; rg < 4; ++rg) {
        const int l = mt*16 + kg*4 + rg, r = nt*16 + l15;
        part += acc[rg] * bf2f(sMeIT[r*64 + swzi(r, l)]);
      }
      part += __shfl_xor(part, 16);
      part += __shfl_xor(part, 32);
      if (lane < 16) atomicAdd(&sQqI[nt*16 + l15], part);
    }
  }
  __syncthreads();

  // ---- Epilogue ----
  if (tid < LN) {
    const float invd = sInvT[tid];
    const float w2 = sqrtf(fmaxf(sQqT[tid]*invd*invd, 1e-16f));
    const float sim = (sW12t[tid]*invd) * __builtin_amdgcn_rcpf(fmaxf(sCapN[tid]*w2, EPSF));
    sEt[tid] = (tid < nw) ? __expf(LLSE*sim) : 0.f;
  }
  if (tid >= 64 && tid < 64+RN) {
    const int r = tid - 64;
    const float invd = sInvI[r];
    const float w2 = sqrtf(fmaxf(sQqI[r]*invd*invd, 1e-16f));
    const float sim = (sW12i[r]*invd) * __builtin_amdgcn_rcpf(fmaxf(sImgN[r]*w2, EPSF));
    sEi[r] = __expf(LLSE*sim);
  }
  __syncthreads();
  if (tid == 0) {
    float st = 0.f, si2 = 0.f;
    for (int l = 0; l < LN; ++l) st += sEt[l];
    for (int r = 0; r < RN; ++r) si2 += sEi[r];
    scores[(size_t)it*CN + c] = __logf(st)/LLSE + __logf(si2)/LLSE;
  }
}

// ---------------- Kernel 4: margin ranking loss ----------------
__global__ __launch_bounds__(128) void loss_kernel(
    const float* __restrict__ S, float* __restrict__ out)
{
  __shared__ float red[128];
  const int t = threadIdx.x;
  const float d = S[t*CN + t];
  float m1 = -1e30f, m2 = -1e30f;
  for (int cc = 0; cc < CN; ++cc)
    if (cc != t) m1 = fmaxf(m1, 0.2f + S[t*CN+cc] - d);
  for (int i2 = 0; i2 < INN; ++i2)
    if (i2 != t) m2 = fmaxf(m2, 0.2f + S[i2*CN+t] - d);
  red[t] = fmaxf(m1, 0.f) + fmaxf(m2, 0.f);
  __syncthreads();
  for (int s = 64; s > 0; s >>= 1) {
    if (t < s) red[t] += red[t+s];
    __syncthreads();
  }
  if (t == 0) out[0] = red[0];
}

extern "C" void kernel_launch(void* const* d_in, const int* in_sizes, int n_in,
                              void* d_out, int out_size, void* d_ws, size_t ws_size,
                              hipStream_t stream) {
  (void)in_sizes; (void)n_in; (void)out_size;
  const float* imgs = (const float*)d_in[0];
  const float* caps = (const float*)d_in[1];
  const int*   lens = (const int*)d_in[2];

  const size_t bfUS = 2*((size_t)MT + NT)*DN;
  const size_t gbUS = (size_t)(INN + CN)*3072;   // padded bf16 G planes
  const size_t smallF = (size_t)INN*RN*RN + INN*RN + (size_t)CN*LN*LN + CN*LN + (size_t)INN*CN;
  int g = CN;
  while (g > 8) {
    const size_t need = (bfUS + gbUS)*2 + (smallF + (size_t)g*LN*NT)*4;
    if (need <= ws_size) break;
    g >>= 1;
  }

  ushort* aHi = (ushort*)d_ws;
  ushort* aLo = aHi + (size_t)MT*DN;   // unused slot (layout stability)
  ushort* bHi = aLo + (size_t)MT*DN;
  ushort* bLo = bHi + (size_t)NT*DN;
  ushort* gIb = bLo + (size_t)NT*DN;   // [128][48*64]
  ushort* gCb = gIb + (size_t)INN*3072;
  float* fbase = (float*)(gCb + (size_t)CN*3072);
  float* gI     = fbase;
  float* nI     = gI + (size_t)INN*RN*RN;
  float* gC     = nI + (size_t)INN*RN;
  float* nC     = gC + (size_t)CN*LN*LN;
  float* scores = nC + (size_t)CN*LN;
  float* dots   = scores + (size_t)INN*CN;

  gram_conv_kernel<<<dim3(INN+CN), dim3(256), 0, stream>>>(
      imgs, caps, gI, nI, gC, nC, aHi, bHi, bLo, gIb, gCb);
  for (int c0 = 0; c0 < CN; c0 += g) {
    dots_gemm_mfma<<<dim3(NT/128, g*LN/128), dim3(256), 0, stream>>>(
        aHi, bHi, bLo, dots, c0*LN);
    attn_kernel<<<dim3(INN, g), dim3(256), 0, stream>>>(
        dots, lens, gIb, gCb, nI, nC, scores, c0);
  }
  loss_kernel<<<dim3(1), dim3(128), 0, stream>>>(scores, (float*)d_out);
}